// Round 9
// baseline (153.579 us; speedup 1.0000x reference)
//
#include <hip/hip_runtime.h>
#include <stdint.h>

#define DEV __device__ __forceinline__

using bf16x8 = __attribute__((ext_vector_type(8))) short;
using f32x4  = __attribute__((ext_vector_type(4))) float;

DEV float b2f(uint16_t h){ return __uint_as_float(((uint32_t)h)<<16); }
DEV uint16_t f2b(float f){ uint32_t u=__float_as_uint(f); u += 0x7fffu + ((u>>16)&1u); return (uint16_t)(u>>16); }
// pack two f32 -> (bf16(a) | bf16(b)<<16), truncating round (1 v_perm_b32)
DEV uint32_t pk2(float a, float b){
  return __builtin_amdgcn_perm(__float_as_uint(b), __float_as_uint(a), 0x07060302u);
}

// async global->LDS, 16B per lane (GEMM staging only)
#define GLOAD16(gp, lp) __builtin_amdgcn_global_load_lds( \
    (__attribute__((address_space(1))) void*)(gp), \
    (__attribute__((address_space(3))) void*)(lp), 16, 0, 0)

constexpr int S_    = 2048;
constexpr int HID   = 896;
constexpr int NH    = 14;
constexpr int NKV   = 2;
constexpr int HD    = 64;
constexpr int BATCH = 2;
constexpr int MROWS = BATCH * S_;   // 4096
constexpr int NQKV  = 1152;         // 896 + 128 + 128
constexpr int SROWS = 1536;         // rows s in [512,2048) have split partials
constexpr int OPSTR = BATCH * NH * SROWS * 64;   // elements per partial slot
constexpr int MLSTR = BATCH * NH * SROWS;        // float2 per partial slot
// log2(e) folded into Q scale: scores come out in log2-domain, exp -> native exp2
constexpr float QSCALE = 0.125f * 1.4426950408889634f;

// ---------------- elementwise f32 -> bf16 (4/thread) ----------------
__global__ void cvt_x_kernel(const float* __restrict__ in, uint16_t* __restrict__ out) {
  int i = blockIdx.x * 256 + threadIdx.x;
  float4 v = ((const float4*)in)[i];
  union { uint16_t u[4]; uint64_t q; } r;
  r.u[0] = f2b(v.x); r.u[1] = f2b(v.y); r.u[2] = f2b(v.z); r.u[3] = f2b(v.w);
  ((uint64_t*)out)[i] = r.q;
}

// ---- weight pack: W (896 x ncols, f32) -> rows [rowOff, rowOff+ncols) of B^T (x896, bf16)
__global__ void pack_wT_kernel(const float* __restrict__ in, uint16_t* __restrict__ out,
                               int ncols, int rowOff) {
  __shared__ uint16_t tile[32][33];
  int n0 = blockIdx.x * 32, k0 = blockIdx.y * 32;
  int lx = threadIdx.x, ly = threadIdx.y;   // 32 x 8
  #pragma unroll
  for (int i = 0; i < 32; i += 8)
    tile[ly + i][lx] = f2b(in[(size_t)(k0 + ly + i) * ncols + (n0 + lx)]);
  __syncthreads();
  #pragma unroll
  for (int i = 0; i < 32; i += 8)
    out[(size_t)(rowOff + n0 + ly + i) * 896 + (k0 + lx)] = tile[lx][ly + i];
}

// ---------------- concat bias bq|bk|bv -> f32[1152] ----------------
__global__ void pack_bias_kernel(const float* __restrict__ bq, const float* __restrict__ bk,
                                 const float* __restrict__ bv, float* __restrict__ out) {
  int i = blockIdx.x * 256 + threadIdx.x;
  if (i >= NQKV) return;
  out[i] = i < 896 ? bq[i] : (i < 1024 ? bk[i - 896] : bv[i - 1024]);
}

// ---------------- RoPE cos/sin table (S x 32, f32) ----------------
__global__ void rope_table_kernel(const int* __restrict__ pos0,
                                  float* __restrict__ cosT, float* __restrict__ sinT) {
  int idx = blockIdx.x * 256 + threadIdx.x;   // S*32
  int s = idx >> 5, j = idx & 31;
  float inv = exp2f(-(float)j * (19.931568569324174f / 32.0f));  // 1e6^(-j/32)
  float ang = (float)(pos0[0] + s) * inv;
  float sv, cv;
  sincosf(ang, &sv, &cv);
  cosT[idx] = cv; sinT[idx] = sv;
}

// ---------------- V: Vf (B,S,128) -> V^T (B,KV,D,S), LDS tile transpose ----------------
__global__ void packv_kernel(const uint16_t* __restrict__ Vf, uint16_t* __restrict__ Vt) {
  __shared__ uint16_t tile[64][65];
  const int s0 = blockIdx.x * 64;
  const int g  = blockIdx.y;                  // b*NKV + kv
  const int b = g >> 1, kv = g & 1;
  const int lx = threadIdx.x & 63, ly = threadIdx.x >> 6;   // 64 x 4
  #pragma unroll
  for (int i = 0; i < 64; i += 4)
    tile[ly + i][lx] = Vf[(size_t)(b * S_ + s0 + ly + i) * 128 + kv * 64 + lx];
  __syncthreads();
  #pragma unroll
  for (int i = 0; i < 64; i += 4)
    Vt[((size_t)g * HD + ly + i) * S_ + s0 + lx] = tile[lx][ly + i];
}

// ---------------- GEMM: C(MxN) = A(MxK,bf16) * Bt(NxK,bf16)^T + bias ----------------
// Tile 128x64, 4 waves of 32x64 (acc[2][4]). EPI 0: f32 C. EPI 1: fused QKV->RoPE.
template <int EPI>
__global__ __launch_bounds__(256) void gemm_bt_kernel(
    const uint16_t* __restrict__ A, const uint16_t* __restrict__ Bt,
    const float* __restrict__ bias, void* __restrict__ Cv, int N, int K,
    const float* __restrict__ cosT, const float* __restrict__ sinT,
    uint16_t* __restrict__ Qb, uint16_t* __restrict__ Kb, uint16_t* __restrict__ Vf) {
  __shared__ __align__(16) uint16_t As[128 * 64];   // 16 KB
  __shared__ __align__(16) uint16_t Bs[64 * 64];    // 8 KB
  const int tid = threadIdx.x;
  const int l = tid & 63, w = tid >> 6;
  const int m0 = blockIdx.x * 128, n0 = blockIdx.y * 64;
  const int wr = w * 32;                            // 32 rows per wave, all 64 cols

  f32x4 acc[2][4] = {};
  for (int k0 = 0; k0 < K; k0 += 64) {
    #pragma unroll
    for (int i = 0; i < 4; ++i) {
      int cid = i * 256 + tid;                 // 1024 A-chunks
      int row = cid >> 3;
      int sch = (cid & 7) ^ (row & 7);
      GLOAD16(A + (size_t)(m0 + row) * K + (k0 + sch * 8), (char*)As + cid * 16);
    }
    #pragma unroll
    for (int i = 0; i < 2; ++i) {
      int cid = i * 256 + tid;                 // 512 B-chunks
      int row = cid >> 3;
      int sch = (cid & 7) ^ (row & 7);
      GLOAD16(Bt + (size_t)(n0 + row) * K + (k0 + sch * 8), (char*)Bs + cid * 16);
    }
    __syncthreads();
    __builtin_amdgcn_s_setprio(1);
    #pragma unroll
    for (int ks = 0; ks < 2; ++ks) {
      bf16x8 af[2], bfr[4];
      #pragma unroll
      for (int mi = 0; mi < 2; ++mi) {
        int row = wr + mi * 16 + (l & 15);
        int ch = ((l >> 4) + ks * 4) ^ (row & 7);
        af[mi] = *(const bf16x8*)((const char*)As + row * 128 + ch * 16);
      }
      #pragma unroll
      for (int ni = 0; ni < 4; ++ni) {
        int row = ni * 16 + (l & 15);
        int ch = ((l >> 4) + ks * 4) ^ (row & 7);
        bfr[ni] = *(const bf16x8*)((const char*)Bs + row * 128 + ch * 16);
      }
      #pragma unroll
      for (int mi = 0; mi < 2; ++mi)
        #pragma unroll
        for (int ni = 0; ni < 4; ++ni)
          acc[mi][ni] = __builtin_amdgcn_mfma_f32_16x16x32_bf16(af[mi], bfr[ni], acc[mi][ni], 0, 0, 0);
    }
    __builtin_amdgcn_s_setprio(0);
    __syncthreads();
  }

  const int tc = l & 15, g = l >> 4;
  if (EPI == 1) {
    if (n0 < 896) {
      // Q head h = n0>>6: RoPE pairs (ni, ni+2), scale QSCALE (1/8 * log2e)
      #pragma unroll
      for (int mi = 0; mi < 2; ++mi) {
        #pragma unroll
        for (int jr = 0; jr < 4; ++jr) {
          int row = m0 + wr + mi * 16 + g * 4 + jr;
          int bb = row >> 11, s = row & (S_ - 1);
          const float* cp = cosT + s * 32;
          const float* sp = sinT + s * 32;
          #pragma unroll
          for (int ni = 0; ni < 2; ++ni) {
            int col = n0 + ni * 16 + tc;
            int j = col & 63;   // < 32
            float c = cp[j], sn = sp[j];
            float alo = acc[mi][ni][jr] + bias[col];
            float ahi = acc[mi][ni + 2][jr] + bias[col + 32];
            size_t dst = ((size_t)(bb * NH + (n0 >> 6)) * S_ + s) * HD + j;
            Qb[dst]      = f2b((alo * c - ahi * sn) * QSCALE);
            Qb[dst + 32] = f2b((ahi * c + alo * sn) * QSCALE);
          }
        }
      }
    } else if (n0 < 1024) {
      // K head kvh = (n0-896)>>6: RoPE, no scale
      #pragma unroll
      for (int mi = 0; mi < 2; ++mi) {
        #pragma unroll
        for (int jr = 0; jr < 4; ++jr) {
          int row = m0 + wr + mi * 16 + g * 4 + jr;
          int bb = row >> 11, s = row & (S_ - 1);
          const float* cp = cosT + s * 32;
          const float* sp = sinT + s * 32;
          #pragma unroll
          for (int ni = 0; ni < 2; ++ni) {
            int col = n0 + ni * 16 + tc;
            int j = col & 63;   // < 32
            float c = cp[j], sn = sp[j];
            float alo = acc[mi][ni][jr] + bias[col];
            float ahi = acc[mi][ni + 2][jr] + bias[col + 32];
            size_t dst = ((size_t)(bb * NKV + ((n0 - 896) >> 6)) * S_ + s) * HD + j;
            Kb[dst]      = f2b(alo * c - ahi * sn);
            Kb[dst + 32] = f2b(ahi * c + alo * sn);
          }
        }
      }
    } else {
      // V block: plain bf16, row-major Vf (B*S, 128)
      #pragma unroll
      for (int mi = 0; mi < 2; ++mi)
        #pragma unroll
        for (int ni = 0; ni < 4; ++ni) {
          int col = n0 + ni * 16 + tc;
          #pragma unroll
          for (int jr = 0; jr < 4; ++jr) {
            int row = m0 + wr + mi * 16 + g * 4 + jr;
            Vf[(size_t)row * 128 + (col - 1024)] = f2b(acc[mi][ni][jr] + bias[col]);
          }
        }
    }
  } else {
    #pragma unroll
    for (int mi = 0; mi < 2; ++mi) {
      #pragma unroll
      for (int ni = 0; ni < 4; ++ni) {
        int col = n0 + ni * 16 + tc;
        #pragma unroll
        for (int j = 0; j < 4; ++j) {
          int row = m0 + wr + mi * 16 + g * 4 + j;
          ((float*)Cv)[(size_t)row * N + col] = acc[mi][ni][j];
        }
      }
    }
  }
}

// ---------------- Flash attention v9: no LDS, no barriers, direct-L2 fragments ----------
// Each wave independent: (head, 32-row q-tile as two 16-row subtiles, kv-chunk <=8 tiles).
// K/V fragments loaded straight from global (L2-resident: 2 MB per (b,kv)).
// Lane-local softmax in exp2-domain (log2e folded into Q), defer-max THR=11.5.
__global__ __launch_bounds__(256) void attn_kernel(
    const uint16_t* __restrict__ Qb, const uint16_t* __restrict__ Kb,
    const uint16_t* __restrict__ Vt, uint16_t* __restrict__ Ob,
    uint16_t* __restrict__ Op, float2* __restrict__ mlp) {
  const int l = threadIdx.x & 63, w = threadIdx.x >> 6;
  const int wu = blockIdx.x * 4 + w;          // wave-unit 0..159
  const int h = blockIdx.y, b = blockIdx.z;
  const int kv = h / 7;
  const int tc = l & 15, g = l >> 4;
  const int srcA = (((2 * g) & 3) << 4) | tc;
  const int srcB = (((2 * g + 1) & 3) << 4) | tc;

  // decode (q32, ck): q32 0..15 ->1 chunk, 16..31 ->2, 32..47 ->3, 48..63 ->4
  int q32, ck;
  if (wu < 16)      { q32 = wu;                 ck = 0; }
  else if (wu < 48) { int i = wu - 16; q32 = 16 + (i >> 1); ck = i & 1; }
  else if (wu < 96) { int i = wu - 48; int q3 = i / 3; q32 = 32 + q3; ck = i - 3 * q3; }
  else              { int i = wu - 96; q32 = 48 + (i >> 2); ck = i & 3; }
  const int ntiles = (q32 >> 1) + 1;
  const int nch    = (ntiles + 7) >> 3;
  const int tlo    = 8 * ck;
  const int thi    = (tlo + 8 < ntiles) ? (tlo + 8) : ntiles;
  const bool split = (nch > 1);

  const int qgA = q32 * 32 + tc;     // subtile A rows
  const int qgB = qgA + 16;          // subtile B rows

  const uint16_t* Khead = Kb + (size_t)(b * NKV + kv) * S_ * HD;
  const uint16_t* Vhead = Vt + (size_t)(b * NKV + kv) * HD * S_;

  // Q fragments (pre-scaled by QSCALE)
  const uint16_t* qpA = Qb + ((size_t)(b * NH + h) * S_ + qgA) * HD + g * 8;
  const uint16_t* qpB = qpA + (size_t)16 * HD;
  bf16x8 qA0 = *(const bf16x8*)qpA, qA1 = *(const bf16x8*)(qpA + 32);
  bf16x8 qB0 = *(const bf16x8*)qpB, qB1 = *(const bf16x8*)(qpB + 32);

  f32x4 oA[4] = {}, oB[4] = {};
  float mA = -1e30f, lA = 0.f, mB = -1e30f, lB = 0.f;   // lane-partial l

  #pragma unroll 1
  for (int t = tlo; t < thi; ++t) {
    const int t0 = t * 64;
    const uint16_t* Kt = Khead + (size_t)t0 * HD;
    const uint16_t* Vt0 = Vhead + t0;

    // S^T = K * Q^T for both subtiles off shared K fragments
    f32x4 sA[4] = {}, sB[4] = {};
    __builtin_amdgcn_s_setprio(1);
    #pragma unroll
    for (int ks = 0; ks < 2; ++ks) {
      bf16x8 qfA = ks ? qA1 : qA0;
      bf16x8 qfB = ks ? qB1 : qB0;
      #pragma unroll
      for (int c = 0; c < 4; ++c) {
        bf16x8 kf = *(const bf16x8*)(Kt + (size_t)(c * 16 + tc) * HD + (ks * 4 + g) * 8);
        sA[c] = __builtin_amdgcn_mfma_f32_16x16x32_bf16(kf, qfA, sA[c], 0, 0, 0);
        sB[c] = __builtin_amdgcn_mfma_f32_16x16x32_bf16(kf, qfB, sB[c], 0, 0, 0);
      }
    }
    __builtin_amdgcn_s_setprio(0);

    // causal mask on the final tile only (provably the only tile needing it)
    if (t == ntiles - 1) {
      #pragma unroll
      for (int c = 0; c < 4; ++c) {
        int kvb = t0 + c * 16 + g * 4;
        #pragma unroll
        for (int r = 0; r < 4; ++r) {
          if (kvb + r > qgA) sA[c][r] = -1e30f;
          if (kvb + r > qgB) sB[c][r] = -1e30f;
        }
      }
    }

    // defer-max (exp2 domain, THR = 8*log2e ~ 11.5)
    float pA = sA[0][0], pB = sB[0][0];
    #pragma unroll
    for (int c = 0; c < 4; ++c)
      #pragma unroll
      for (int r = 0; r < 4; ++r) { pA = fmaxf(pA, sA[c][r]); pB = fmaxf(pB, sB[c][r]); }
    if (__any(fmaxf(pA - mA, pB - mB) > 11.5f)) {
      float mtA = fmaxf(pA, __shfl_xor(pA, 16)); mtA = fmaxf(mtA, __shfl_xor(mtA, 32));
      float mtB = fmaxf(pB, __shfl_xor(pB, 16)); mtB = fmaxf(mtB, __shfl_xor(mtB, 32));
      float mnA = fmaxf(mA, mtA), mnB = fmaxf(mB, mtB);
      float cA = exp2f(mA - mnA), cB = exp2f(mB - mnB);
      mA = mnA; mB = mnB; lA *= cA; lB *= cB;
      #pragma unroll
      for (int dt = 0; dt < 4; ++dt) { oA[dt] *= cA; oB[dt] *= cB; }
    }
    float rsA = 0.f, rsB = 0.f;
    #pragma unroll
    for (int c = 0; c < 4; ++c)
      #pragma unroll
      for (int r = 0; r < 4; ++r) {
        float eA = exp2f(sA[c][r] - mA); sA[c][r] = eA; rsA += eA;
        float eB = exp2f(sB[c][r] - mB); sB[c][r] = eB; rsB += eB;
      }
    lA += rsA; lB += rsB;

    // pack P -> bf16, redistribute into PV B-fragments (per subtile)
    bf16x8 pfA[2], pfB[2];
    {
      uint32_t wA0[4], wA1[4], wB0[4], wB1[4];
      #pragma unroll
      for (int c = 0; c < 4; ++c) {
        wA0[c] = pk2(sA[c][0], sA[c][1]); wA1[c] = pk2(sA[c][2], sA[c][3]);
        wB0[c] = pk2(sB[c][0], sB[c][1]); wB1[c] = pk2(sB[c][2], sB[c][3]);
      }
      const bool lo = g < 2;
      union { uint32_t u[4]; bf16x8 v; } t0u, t1u;
      #pragma unroll
      for (int sb = 0; sb < 2; ++sb) {
        uint32_t* w0 = sb ? wB0 : wA0;
        uint32_t* w1 = sb ? wB1 : wA1;
        uint32_t a0 = __shfl((int)w0[0], srcA), a1 = __shfl((int)w1[0], srcA);
        uint32_t a2 = __shfl((int)w0[0], srcB), a3 = __shfl((int)w1[0], srcB);
        uint32_t b0 = __shfl((int)w0[1], srcA), b1 = __shfl((int)w1[1], srcA);
        uint32_t b2 = __shfl((int)w0[1], srcB), b3 = __shfl((int)w1[1], srcB);
        t0u.u[0] = lo ? a0 : b0; t0u.u[1] = lo ? a1 : b1;
        t0u.u[2] = lo ? a2 : b2; t0u.u[3] = lo ? a3 : b3;
        uint32_t c0 = __shfl((int)w0[2], srcA), c1 = __shfl((int)w1[2], srcA);
        uint32_t c2 = __shfl((int)w0[2], srcB), c3 = __shfl((int)w1[2], srcB);
        uint32_t d0 = __shfl((int)w0[3], srcA), d1 = __shfl((int)w1[3], srcA);
        uint32_t d2 = __shfl((int)w0[3], srcB), d3 = __shfl((int)w1[3], srcB);
        t1u.u[0] = lo ? c0 : d0; t1u.u[1] = lo ? c1 : d1;
        t1u.u[2] = lo ? c2 : d2; t1u.u[3] = lo ? c3 : d3;
        if (sb) { pfB[0] = t0u.v; pfB[1] = t1u.v; }
        else    { pfA[0] = t0u.v; pfA[1] = t1u.v; }
      }
    }

    // O^T += V^T * P^T, shared V fragments
    __builtin_amdgcn_s_setprio(1);
    #pragma unroll
    for (int ks = 0; ks < 2; ++ks) {
      #pragma unroll
      for (int dt = 0; dt < 4; ++dt) {
        bf16x8 vf = *(const bf16x8*)(Vt0 + (size_t)(dt * 16 + tc) * S_ + (ks * 4 + g) * 8);
        oA[dt] = __builtin_amdgcn_mfma_f32_16x16x32_bf16(vf, pfA[ks], oA[dt], 0, 0, 0);
        oB[dt] = __builtin_amdgcn_mfma_f32_16x16x32_bf16(vf, pfB[ks], oB[dt], 0, 0, 0);
      }
    }
    __builtin_amdgcn_s_setprio(0);
  }

  // reduce lane-partial l across the 4 lane-groups
  float ltA = lA; ltA += __shfl_xor(ltA, 16); ltA += __shfl_xor(ltA, 32);
  float ltB = lB; ltB += __shfl_xor(ltB, 16); ltB += __shfl_xor(ltB, 32);

  if (!split) {
    float iA = 1.0f / ltA, iB = 1.0f / ltB;
    size_t baseA = (size_t)(b * S_ + qgA) * HID + h * HD;
    size_t baseB = (size_t)(b * S_ + qgB) * HID + h * HD;
    #pragma unroll
    for (int dt = 0; dt < 4; ++dt) {
      union { uint16_t u[4]; uint64_t q; } a, bb_;
      #pragma unroll
      for (int r = 0; r < 4; ++r) { a.u[r] = f2b(oA[dt][r] * iA); bb_.u[r] = f2b(oB[dt][r] * iB); }
      *(uint64_t*)(Ob + baseA + dt * 16 + g * 4) = a.q;
      *(uint64_t*)(Ob + baseB + dt * 16 + g * 4) = bb_.q;
    }
  } else {
    size_t ridA = (size_t)(b * NH + h) * SROWS + (qgA - 512);
    size_t ridB = ridA + 16;
    uint16_t* OpA = Op + (size_t)ck * OPSTR + ridA * 64;
    uint16_t* OpB = Op + (size_t)ck * OPSTR + ridB * 64;
    #pragma unroll
    for (int dt = 0; dt < 4; ++dt) {
      union { uint16_t u[4]; uint64_t q; } a, bb_;
      #pragma unroll
      for (int r = 0; r < 4; ++r) { a.u[r] = f2b(oA[dt][r]); bb_.u[r] = f2b(oB[dt][r]); }
      *(uint64_t*)(OpA + dt * 16 + g * 4) = a.q;
      *(uint64_t*)(OpB + dt * 16 + g * 4) = bb_.q;
    }
    if (g == 0) {
      mlp[(size_t)ck * MLSTR + ridA] = make_float2(mA, ltA);
      mlp[(size_t)ck * MLSTR + ridB] = make_float2(mB, ltB);
    }
  }
}

// ---------------- combine up to 4 partials for rows s >= 512 (exp2 domain) ----------------
__global__ void combine_kernel(const uint16_t* __restrict__ Op, const float2* __restrict__ mlp,
                               uint16_t* __restrict__ Ob) {
  int idx = blockIdx.x * 256 + threadIdx.x;   // B*NH*SROWS*16
  int r = idx >> 4;                           // (b*NH+h)*SROWS + (s-512)
  int d0 = (idx & 15) * 4;
  int bh = r / SROWS;
  int sr = r - bh * SROWS;
  int s = 512 + sr;
  int nch = (s >> 9) + 1;                     // 2..4
  float M = -1e30f;
  #pragma unroll 4
  for (int c = 0; c < 4; ++c)
    if (c < nch) M = fmaxf(M, mlp[(size_t)c * MLSTR + r].x);
  float den = 0.f, acc[4] = {0.f, 0.f, 0.f, 0.f};
  #pragma unroll 4
  for (int c = 0; c < 4; ++c) {
    if (c >= nch) continue;
    float2 ml = mlp[(size_t)c * MLSTR + r];
    float wg = exp2f(ml.x - M);
    den += ml.y * wg;
    union { uint16_t u[4]; uint64_t q; } o;
    o.q = *(const uint64_t*)(Op + (size_t)c * OPSTR + (size_t)r * 64 + d0);
    #pragma unroll
    for (int j = 0; j < 4; ++j) acc[j] += b2f(o.u[j]) * wg;
  }
  float inv = 1.0f / den;
  union { uint16_t u[4]; uint64_t q; } oo;
  #pragma unroll
  for (int j = 0; j < 4; ++j) oo.u[j] = f2b(acc[j] * inv);
  int bb = bh / NH, hh = bh - bb * NH;
  *(uint64_t*)(Ob + (size_t)(bb * S_ + s) * HID + hh * HD + d0) = oo.q;
}

// ---------------- launch ----------------
extern "C" void kernel_launch(void* const* d_in, const int* in_sizes, int n_in,
                              void* d_out, int out_size, void* d_ws, size_t ws_size,
                              hipStream_t stream) {
  (void)in_sizes; (void)n_in; (void)out_size; (void)ws_size;
  const float* X  = (const float*)d_in[0];
  // d_in[1] = attention_mask: pure causal tril, applied analytically in attn_kernel
  const float* Wq = (const float*)d_in[2];
  const float* bq = (const float*)d_in[3];
  const float* Wk = (const float*)d_in[4];
  const float* bk = (const float*)d_in[5];
  const float* Wv = (const float*)d_in[6];
  const float* bv = (const float*)d_in[7];
  const float* Wo = (const float*)d_in[8];
  const int* pos  = (const int*)d_in[9];

  char* p = (char*)d_ws;
  auto carve = [&](size_t n) -> char* { char* r = p; p += (n + 255) & ~(size_t)255; return r; };

  uint16_t* Xb    = (uint16_t*)carve((size_t)MROWS * HID * 2);
  uint16_t* WqkvT = (uint16_t*)carve((size_t)NQKV * 896 * 2);
  uint16_t* WoT   = (uint16_t*)carve((size_t)896 * 896 * 2);
  float*    bqkv  = (float*)carve((size_t)NQKV * 4);
  float*    cosT  = (float*)carve((size_t)S_ * 32 * 4);
  float*    sinT  = (float*)carve((size_t)S_ * 32 * 4);
  uint16_t* Qb    = (uint16_t*)carve((size_t)MROWS * HID * 2);
  uint16_t* Kb    = (uint16_t*)carve((size_t)MROWS * 128 * 2);
  uint16_t* Vf    = (uint16_t*)carve((size_t)MROWS * 128 * 2);
  uint16_t* Vt    = (uint16_t*)carve((size_t)MROWS * 128 * 2);
  uint16_t* Op    = (uint16_t*)carve((size_t)OPSTR * 4 * 2);
  float2*   mlp   = (float2*)carve((size_t)MLSTR * 4 * 8);
  uint16_t* Ob    = Xb;   // Xb dead after QKV gemm; attn/combine write Ob afterwards

  cvt_x_kernel<<<dim3((MROWS * HID / 4) / 256), 256, 0, stream>>>(X, Xb);
  pack_wT_kernel<<<dim3(28, 28), dim3(32, 8), 0, stream>>>(Wq, WqkvT, 896, 0);
  pack_wT_kernel<<<dim3(4, 28),  dim3(32, 8), 0, stream>>>(Wk, WqkvT, 128, 896);
  pack_wT_kernel<<<dim3(4, 28),  dim3(32, 8), 0, stream>>>(Wv, WqkvT, 128, 1024);
  pack_wT_kernel<<<dim3(28, 28), dim3(32, 8), 0, stream>>>(Wo, WoT, 896, 0);
  pack_bias_kernel<<<dim3(5), 256, 0, stream>>>(bq, bk, bv, bqkv);
  rope_table_kernel<<<dim3(S_ * 32 / 256), 256, 0, stream>>>(pos, cosT, sinT);

  gemm_bt_kernel<1><<<dim3(MROWS / 128, NQKV / 64), 256, 0, stream>>>(
      Xb, WqkvT, bqkv, nullptr, NQKV, 896, cosT, sinT, Qb, Kb, Vf);

  packv_kernel<<<dim3(S_ / 64, BATCH * NKV), 256, 0, stream>>>(Vf, Vt);

  attn_kernel<<<dim3(40, NH, BATCH), 256, 0, stream>>>(Qb, Kb, Vt, Ob, Op, mlp);
  combine_kernel<<<dim3(BATCH * NH * SROWS * 16 / 256), 256, 0, stream>>>(Op, mlp, Ob);

  gemm_bt_kernel<0><<<dim3(MROWS / 128, 896 / 64), 256, 0, stream>>>(
      Ob, WoT, nullptr, d_out, 896, 896, nullptr, nullptr, nullptr, nullptr, nullptr);
}

// Round 10
// 104.575 us; speedup vs baseline: 1.4686x; 1.4686x over previous
//
#include <hip/hip_runtime.h>
#include <stdint.h>

#define DEV __device__ __forceinline__

using bf16x8 = __attribute__((ext_vector_type(8))) short;
using f32x4  = __attribute__((ext_vector_type(4))) float;

DEV float b2f(uint16_t h){ return __uint_as_float(((uint32_t)h)<<16); }
DEV uint16_t f2b(float f){ uint32_t u=__float_as_uint(f); u += 0x7fffu + ((u>>16)&1u); return (uint16_t)(u>>16); }
// pack two f32 -> (bf16(a) | bf16(b)<<16), truncating round (1 v_perm_b32)
DEV uint32_t pk2(float a, float b){
  return __builtin_amdgcn_perm(__float_as_uint(b), __float_as_uint(a), 0x07060302u);
}

// async global->LDS, 16B per lane; LDS dest must be wave-uniform base + lane*16
#define GLOAD16(gp, lp) __builtin_amdgcn_global_load_lds( \
    (__attribute__((address_space(1))) void*)(gp), \
    (__attribute__((address_space(3))) void*)(lp), 16, 0, 0)

constexpr int S_    = 2048;
constexpr int HID   = 896;
constexpr int NH    = 14;
constexpr int NKV   = 2;
constexpr int HD    = 64;
constexpr int BATCH = 2;
constexpr int MROWS = BATCH * S_;   // 4096
constexpr int NQKV  = 1152;         // 896 + 128 + 128
constexpr int SROWS = 1536;         // rows s in [512,2048) have split partials
constexpr int OPSTR = BATCH * NH * SROWS * 64;   // elements per partial slot
constexpr int MLSTR = BATCH * NH * SROWS;        // float2 per partial slot
// log2(e) folded into Q scale: scores in log2-domain, exp -> native exp2 (validated R9)
constexpr float QSCALE = 0.125f * 1.4426950408889634f;

// ---------------- elementwise f32 -> bf16 (4/thread) ----------------
__global__ void cvt_x_kernel(const float* __restrict__ in, uint16_t* __restrict__ out) {
  int i = blockIdx.x * 256 + threadIdx.x;
  float4 v = ((const float4*)in)[i];
  union { uint16_t u[4]; uint64_t q; } r;
  r.u[0] = f2b(v.x); r.u[1] = f2b(v.y); r.u[2] = f2b(v.z); r.u[3] = f2b(v.w);
  ((uint64_t*)out)[i] = r.q;
}

// ---- merged weight pack + bias concat (was 5 kernels) ----
// jobs: [0,784) Wq->WqkvT@0 ; [784,896) Wk->WqkvT@896 ; [896,1008) Wv->WqkvT@1024 ;
//       [1008,1792) Wo->WoT@0 ; [1792,1797) bias concat.
__global__ void pack_all_kernel(const float* __restrict__ Wq, const float* __restrict__ Wk,
                                const float* __restrict__ Wv, const float* __restrict__ Wo,
                                const float* __restrict__ bq, const float* __restrict__ bk,
                                const float* __restrict__ bv,
                                uint16_t* __restrict__ WqkvT, uint16_t* __restrict__ WoT,
                                float* __restrict__ bqkv) {
  const int blk = blockIdx.x;
  const int lx = threadIdx.x, ly = threadIdx.y;   // 32 x 8
  if (blk >= 1792) {                               // bias
    int i = (blk - 1792) * 256 + ly * 32 + lx;
    if (i < NQKV) bqkv[i] = i < 896 ? bq[i] : (i < 1024 ? bk[i - 896] : bv[i - 1024]);
    return;
  }
  const float* src; uint16_t* dst; int ncols, rowOff, i;
  if (blk < 784)       { src = Wq; dst = WqkvT; ncols = 896; rowOff = 0;    i = blk;        }
  else if (blk < 896)  { src = Wk; dst = WqkvT; ncols = 128; rowOff = 896;  i = blk - 784;  }
  else if (blk < 1008) { src = Wv; dst = WqkvT; ncols = 128; rowOff = 1024; i = blk - 896;  }
  else                 { src = Wo; dst = WoT;   ncols = 896; rowOff = 0;    i = blk - 1008; }
  const int nb = ncols >> 5;
  const int n0 = (i % nb) * 32, k0 = (i / nb) * 32;
  __shared__ uint16_t tile[32][33];
  #pragma unroll
  for (int r = 0; r < 32; r += 8)
    tile[ly + r][lx] = f2b(src[(size_t)(k0 + ly + r) * ncols + (n0 + lx)]);
  __syncthreads();
  #pragma unroll
  for (int r = 0; r < 32; r += 8)
    dst[(size_t)(rowOff + n0 + ly + r) * 896 + (k0 + lx)] = tile[lx][ly + r];
}

// ---------------- RoPE cos/sin table (S x 32, f32) ----------------
__global__ void rope_table_kernel(const int* __restrict__ pos0,
                                  float* __restrict__ cosT, float* __restrict__ sinT) {
  int idx = blockIdx.x * 256 + threadIdx.x;   // S*32
  int s = idx >> 5, j = idx & 31;
  float inv = exp2f(-(float)j * (19.931568569324174f / 32.0f));  // 1e6^(-j/32)
  float ang = (float)(pos0[0] + s) * inv;
  float sv, cv;
  sincosf(ang, &sv, &cv);
  cosT[idx] = cv; sinT[idx] = sv;
}

// ---------------- V: Vf (B,S,128) -> V^T (B,KV,D,S), LDS tile transpose ----------------
__global__ void packv_kernel(const uint16_t* __restrict__ Vf, uint16_t* __restrict__ Vt) {
  __shared__ uint16_t tile[64][65];
  const int s0 = blockIdx.x * 64;
  const int g  = blockIdx.y;                  // b*NKV + kv
  const int b = g >> 1, kv = g & 1;
  const int lx = threadIdx.x & 63, ly = threadIdx.x >> 6;   // 64 x 4
  #pragma unroll
  for (int i = 0; i < 64; i += 4)
    tile[ly + i][lx] = Vf[(size_t)(b * S_ + s0 + ly + i) * 128 + kv * 64 + lx];
  __syncthreads();
  #pragma unroll
  for (int i = 0; i < 64; i += 4)
    Vt[((size_t)g * HD + ly + i) * S_ + s0 + lx] = tile[lx][ly + i];
}

// ---------------- GEMM: C(MxN) = A(MxK,bf16) * Bt(NxK,bf16)^T + bias ----------------
// Tile 128x64, 4 waves of 32x64 (acc[2][4]). EPI 0: f32 C. EPI 1: fused QKV->RoPE.
template <int EPI>
__global__ __launch_bounds__(256) void gemm_bt_kernel(
    const uint16_t* __restrict__ A, const uint16_t* __restrict__ Bt,
    const float* __restrict__ bias, void* __restrict__ Cv, int N, int K,
    const float* __restrict__ cosT, const float* __restrict__ sinT,
    uint16_t* __restrict__ Qb, uint16_t* __restrict__ Kb, uint16_t* __restrict__ Vf) {
  __shared__ __align__(16) uint16_t As[128 * 64];   // 16 KB
  __shared__ __align__(16) uint16_t Bs[64 * 64];    // 8 KB
  const int tid = threadIdx.x;
  const int l = tid & 63, w = tid >> 6;
  const int m0 = blockIdx.x * 128, n0 = blockIdx.y * 64;
  const int wr = w * 32;                            // 32 rows per wave, all 64 cols

  f32x4 acc[2][4] = {};
  for (int k0 = 0; k0 < K; k0 += 64) {
    #pragma unroll
    for (int i = 0; i < 4; ++i) {
      int cid = i * 256 + tid;                 // 1024 A-chunks
      int row = cid >> 3;
      int sch = (cid & 7) ^ (row & 7);
      GLOAD16(A + (size_t)(m0 + row) * K + (k0 + sch * 8), (char*)As + cid * 16);
    }
    #pragma unroll
    for (int i = 0; i < 2; ++i) {
      int cid = i * 256 + tid;                 // 512 B-chunks
      int row = cid >> 3;
      int sch = (cid & 7) ^ (row & 7);
      GLOAD16(Bt + (size_t)(n0 + row) * K + (k0 + sch * 8), (char*)Bs + cid * 16);
    }
    __syncthreads();
    __builtin_amdgcn_s_setprio(1);
    #pragma unroll
    for (int ks = 0; ks < 2; ++ks) {
      bf16x8 af[2], bfr[4];
      #pragma unroll
      for (int mi = 0; mi < 2; ++mi) {
        int row = wr + mi * 16 + (l & 15);
        int ch = ((l >> 4) + ks * 4) ^ (row & 7);
        af[mi] = *(const bf16x8*)((const char*)As + row * 128 + ch * 16);
      }
      #pragma unroll
      for (int ni = 0; ni < 4; ++ni) {
        int row = ni * 16 + (l & 15);
        int ch = ((l >> 4) + ks * 4) ^ (row & 7);
        bfr[ni] = *(const bf16x8*)((const char*)Bs + row * 128 + ch * 16);
      }
      #pragma unroll
      for (int mi = 0; mi < 2; ++mi)
        #pragma unroll
        for (int ni = 0; ni < 4; ++ni)
          acc[mi][ni] = __builtin_amdgcn_mfma_f32_16x16x32_bf16(af[mi], bfr[ni], acc[mi][ni], 0, 0, 0);
    }
    __builtin_amdgcn_s_setprio(0);
    __syncthreads();
  }

  const int tc = l & 15, g = l >> 4;
  if (EPI == 1) {
    if (n0 < 896) {
      // Q head h = n0>>6: RoPE pairs (ni, ni+2), scale QSCALE (1/8 * log2e)
      #pragma unroll
      for (int mi = 0; mi < 2; ++mi) {
        #pragma unroll
        for (int jr = 0; jr < 4; ++jr) {
          int row = m0 + wr + mi * 16 + g * 4 + jr;
          int bb = row >> 11, s = row & (S_ - 1);
          const float* cp = cosT + s * 32;
          const float* sp = sinT + s * 32;
          #pragma unroll
          for (int ni = 0; ni < 2; ++ni) {
            int col = n0 + ni * 16 + tc;
            int j = col & 63;   // < 32
            float c = cp[j], sn = sp[j];
            float alo = acc[mi][ni][jr] + bias[col];
            float ahi = acc[mi][ni + 2][jr] + bias[col + 32];
            size_t dst = ((size_t)(bb * NH + (n0 >> 6)) * S_ + s) * HD + j;
            Qb[dst]      = f2b((alo * c - ahi * sn) * QSCALE);
            Qb[dst + 32] = f2b((ahi * c + alo * sn) * QSCALE);
          }
        }
      }
    } else if (n0 < 1024) {
      // K head kvh = (n0-896)>>6: RoPE, no scale
      #pragma unroll
      for (int mi = 0; mi < 2; ++mi) {
        #pragma unroll
        for (int jr = 0; jr < 4; ++jr) {
          int row = m0 + wr + mi * 16 + g * 4 + jr;
          int bb = row >> 11, s = row & (S_ - 1);
          const float* cp = cosT + s * 32;
          const float* sp = sinT + s * 32;
          #pragma unroll
          for (int ni = 0; ni < 2; ++ni) {
            int col = n0 + ni * 16 + tc;
            int j = col & 63;   // < 32
            float c = cp[j], sn = sp[j];
            float alo = acc[mi][ni][jr] + bias[col];
            float ahi = acc[mi][ni + 2][jr] + bias[col + 32];
            size_t dst = ((size_t)(bb * NKV + ((n0 - 896) >> 6)) * S_ + s) * HD + j;
            Kb[dst]      = f2b(alo * c - ahi * sn);
            Kb[dst + 32] = f2b(ahi * c + alo * sn);
          }
        }
      }
    } else {
      // V block: plain bf16, row-major Vf (B*S, 128)
      #pragma unroll
      for (int mi = 0; mi < 2; ++mi)
        #pragma unroll
        for (int ni = 0; ni < 4; ++ni) {
          int col = n0 + ni * 16 + tc;
          #pragma unroll
          for (int jr = 0; jr < 4; ++jr) {
            int row = m0 + wr + mi * 16 + g * 4 + jr;
            Vf[(size_t)row * 128 + (col - 1024)] = f2b(acc[mi][ni][jr] + bias[col]);
          }
        }
    }
  } else {
    #pragma unroll
    for (int mi = 0; mi < 2; ++mi) {
      #pragma unroll
      for (int ni = 0; ni < 4; ++ni) {
        int col = n0 + ni * 16 + tc;
        #pragma unroll
        for (int j = 0; j < 4; ++j) {
          int row = m0 + wr + mi * 16 + g * 4 + j;
          ((float*)Cv)[(size_t)row * N + col] = acc[mi][ni][j];
        }
      }
    }
  }
}

// ---------------- Flash attention v10: R7 structure + exp2 + LPT order ----------------
// Block = 448 threads, wave w = head kv*7+w, shared K/V LDS tile, depth-1 prefetch.
// Unit u (LPT-reversed): chunks of <=8 kv-tiles. Softmax in exp2 domain (Q pre-scaled
// by log2e/8), defer-max THR = 11.5 (= 8*log2e).
__global__ __launch_bounds__(448) void attn_kernel(
    const uint16_t* __restrict__ Qb, const uint16_t* __restrict__ Kb,
    const uint16_t* __restrict__ Vt, uint16_t* __restrict__ Ob,
    uint16_t* __restrict__ Op, float2* __restrict__ mlp) {
  __shared__ __align__(16) uint16_t Ks[2][64 * 64];   // [kv][d], swizzled
  __shared__ __align__(16) uint16_t Vs[2][64 * 64];   // [d][kv], swizzled
  const int tid = threadIdx.x, l = tid & 63, w = tid >> 6;
  const int u = 319 - blockIdx.x;             // LPT: longest chunks dispatch first
  const int kv = blockIdx.y & 1, b = blockIdx.y >> 1;
  const int tc = l & 15, g = l >> 4;
  const int srcA = (((2 * g) & 3) << 4) | tc;
  const int srcB = (((2 * g + 1) & 3) << 4) | tc;

  // decode (qt16, ck)
  int qt16, ck;
  if (u < 32)       { qt16 = u;                   ck = 0; }
  else if (u < 96)  { int i = u - 32;  qt16 = 32 + (i >> 1); ck = i & 1; }
  else if (u < 192) { int i = u - 96;  int q3 = i / 3; qt16 = 64 + q3; ck = i - 3 * q3; }
  else              { int i = u - 192; qt16 = 96 + (i >> 2); ck = i & 3; }
  const int ntiles = (qt16 >> 2) + 1;
  const int nch    = (qt16 >> 5) + 1;
  const int tlo    = 8 * ck;
  const int thi    = (8 * ck + 8 < ntiles) ? (8 * ck + 8) : ntiles;
  const int ns     = thi - tlo;
  const bool dodiag = (ck == nch - 1);
  const bool split  = (nch > 1);

  const int h  = kv * 7 + w;
  const int qg = qt16 * 16 + tc;

  const uint16_t* Khead = Kb + (size_t)(b * NKV + kv) * S_ * HD;
  const uint16_t* Vhead = Vt + (size_t)(b * NKV + kv) * HD * S_;

  // 64x64 bf16 tile = 512 x 16B chunks: 448 lanes + wave0 covers 448..511.
  auto stage = [&](int t, int bi) {
    const int t0 = t * 64;
    #pragma unroll
    for (int i = 0; i < 2; ++i) {
      if (i == 0 || tid < 64) {                 // wave-uniform predicate
        int cid = i * 448 + tid;                // 0..511
        int row = cid >> 3, sch = (cid & 7) ^ (row & 7);
        GLOAD16(Khead + (size_t)(t0 + row) * HD + sch * 8, (char*)Ks[bi] + cid * 16);
        GLOAD16(Vhead + (size_t)row * S_ + t0 + sch * 8,   (char*)Vs[bi] + cid * 16);
      }
    }
  };

  // Q fragments (pre-scaled by QSCALE): lane owns one q-row (qg), d-slice g*8
  const uint16_t* qptr = Qb + ((size_t)(b * NH + h) * S_ + qg) * HD + g * 8;
  bf16x8 qf0 = *(const bf16x8*)qptr;
  bf16x8 qf1 = *(const bf16x8*)(qptr + 32);

  f32x4 oacc[4] = {};
  float mrow = -1e30f, lrow = 0.f;   // lane-partial over its 16 kv slots

  stage(tlo, 0);

  #pragma unroll 1
  for (int i = 0; i < ns; ++i) {
    const int t = tlo + i;
    asm volatile("s_waitcnt vmcnt(0)" ::: "memory");
    __builtin_amdgcn_s_barrier();
    if (i + 1 < ns) stage(t + 1, (i + 1) & 1);

    const uint16_t* Kc = Ks[i & 1];
    const uint16_t* Vc = Vs[i & 1];
    const int t0 = t * 64;

    // S^T = K * Q^T : sacc[c][r] = S[kv = t0 + c*16 + g*4 + r][q = qg]
    f32x4 sacc[4] = {};
    __builtin_amdgcn_s_setprio(1);
    #pragma unroll
    for (int ks = 0; ks < 2; ++ks) {
      bf16x8 qf = ks ? qf1 : qf0;
      #pragma unroll
      for (int c = 0; c < 4; ++c) {
        int trow = c * 16 + tc;
        int ch = (g + ks * 4) ^ (tc & 7);
        bf16x8 kf = *(const bf16x8*)((const char*)Kc + trow * 128 + ch * 16);
        sacc[c] = __builtin_amdgcn_mfma_f32_16x16x32_bf16(kf, qf, sacc[c], 0, 0, 0);
      }
    }
    __builtin_amdgcn_s_setprio(0);

    // causal mask on diagonal tile only
    if (dodiag && t == ntiles - 1) {
      #pragma unroll
      for (int c = 0; c < 4; ++c) {
        int kvb = t0 + c * 16 + g * 4;
        #pragma unroll
        for (int r = 0; r < 4; ++r)
          if (kvb + r > qg) sacc[c][r] = -1e30f;
      }
    }

    // T13 defer-max (exp2 domain, THR = 8*log2e ~ 11.5)
    float pmax = sacc[0][0];
    #pragma unroll
    for (int c = 0; c < 4; ++c)
      #pragma unroll
      for (int r = 0; r < 4; ++r) pmax = fmaxf(pmax, sacc[c][r]);
    if (__any(pmax > mrow + 11.5f)) {
      float mt = fmaxf(pmax, __shfl_xor(pmax, 16));
      mt = fmaxf(mt, __shfl_xor(mt, 32));
      float mn = fmaxf(mrow, mt);
      float corr = exp2f(mrow - mn);
      mrow = mn;
      lrow *= corr;
      #pragma unroll
      for (int dt = 0; dt < 4; ++dt) oacc[dt] *= corr;
    }
    float rs = 0.f;
    #pragma unroll
    for (int c = 0; c < 4; ++c)
      #pragma unroll
      for (int r = 0; r < 4; ++r) {
        float e = exp2f(sacc[c][r] - mrow);
        sacc[c][r] = e; rs += e;
      }
    lrow += rs;

    // pack P to bf16 words and redistribute into PV B-fragments
    uint32_t w0[4], w1[4];
    #pragma unroll
    for (int c = 0; c < 4; ++c) {
      w0[c] = pk2(sacc[c][0], sacc[c][1]);
      w1[c] = pk2(sacc[c][2], sacc[c][3]);
    }
    const bool lo = g < 2;
    bf16x8 pf[2];
    {
      union { uint32_t u[4]; bf16x8 v; } p0, p1;
      uint32_t a0 = __shfl((int)w0[0], srcA), a1 = __shfl((int)w1[0], srcA);
      uint32_t a2 = __shfl((int)w0[0], srcB), a3 = __shfl((int)w1[0], srcB);
      uint32_t b0 = __shfl((int)w0[1], srcA), b1 = __shfl((int)w1[1], srcA);
      uint32_t b2 = __shfl((int)w0[1], srcB), b3 = __shfl((int)w1[1], srcB);
      p0.u[0] = lo ? a0 : b0; p0.u[1] = lo ? a1 : b1;
      p0.u[2] = lo ? a2 : b2; p0.u[3] = lo ? a3 : b3;
      pf[0] = p0.v;
      uint32_t c0 = __shfl((int)w0[2], srcA), c1 = __shfl((int)w1[2], srcA);
      uint32_t c2 = __shfl((int)w0[2], srcB), c3 = __shfl((int)w1[2], srcB);
      uint32_t d0 = __shfl((int)w0[3], srcA), d1 = __shfl((int)w1[3], srcA);
      uint32_t d2 = __shfl((int)w0[3], srcB), d3 = __shfl((int)w1[3], srcB);
      p1.u[0] = lo ? c0 : d0; p1.u[1] = lo ? c1 : d1;
      p1.u[2] = lo ? c2 : d2; p1.u[3] = lo ? c3 : d3;
      pf[1] = p1.v;
    }

    // O^T += V^T * P^T
    __builtin_amdgcn_s_setprio(1);
    #pragma unroll
    for (int ks = 0; ks < 2; ++ks) {
      #pragma unroll
      for (int dt = 0; dt < 4; ++dt) {
        int drow = dt * 16 + tc;
        int vch = (g + ks * 4) ^ (tc & 7);
        bf16x8 vf = *(const bf16x8*)((const char*)Vc + drow * 128 + vch * 16);
        oacc[dt] = __builtin_amdgcn_mfma_f32_16x16x32_bf16(vf, pf[ks], oacc[dt], 0, 0, 0);
      }
    }
    __builtin_amdgcn_s_setprio(0);
  }

  // combine lane-partial lrow across the 4 lane-groups
  float ltot = lrow;
  ltot += __shfl_xor(ltot, 16);
  ltot += __shfl_xor(ltot, 32);

  if (!split) {
    float inv = 1.0f / ltot;
    size_t obase = (size_t)(b * S_ + qg) * HID + h * HD;
    #pragma unroll
    for (int dt = 0; dt < 4; ++dt) {
      union { uint16_t u[4]; uint64_t q; } o;
      #pragma unroll
      for (int r = 0; r < 4; ++r) o.u[r] = f2b(oacc[dt][r] * inv);
      *(uint64_t*)(Ob + obase + dt * 16 + g * 4) = o.q;
    }
  } else {
    // partial slot ck: unnormalized bf16 O + (m, l)  [m in log2 domain]
    size_t rowid = (size_t)(b * NH + h) * SROWS + (qg - 512);
    uint16_t* Opc = Op + (size_t)ck * OPSTR + rowid * 64;
    #pragma unroll
    for (int dt = 0; dt < 4; ++dt) {
      union { uint16_t u[4]; uint64_t q; } o;
      #pragma unroll
      for (int r = 0; r < 4; ++r) o.u[r] = f2b(oacc[dt][r]);
      *(uint64_t*)(Opc + dt * 16 + g * 4) = o.q;
    }
    if (g == 0) mlp[(size_t)ck * MLSTR + rowid] = make_float2(mrow, ltot);
  }
}

// ---------------- combine up to 4 partials for rows s >= 512 (exp2 domain) ----------------
__global__ void combine_kernel(const uint16_t* __restrict__ Op, const float2* __restrict__ mlp,
                               uint16_t* __restrict__ Ob) {
  int idx = blockIdx.x * 256 + threadIdx.x;   // B*NH*SROWS*16
  int r = idx >> 4;                           // (b*NH+h)*SROWS + (s-512)
  int d0 = (idx & 15) * 4;
  int bh = r / SROWS;
  int sr = r - bh * SROWS;
  int s = 512 + sr;
  int nch = (s >> 9) + 1;                     // 2..4
  float M = -1e30f;
  #pragma unroll 4
  for (int c = 0; c < 4; ++c)
    if (c < nch) M = fmaxf(M, mlp[(size_t)c * MLSTR + r].x);
  float den = 0.f, acc[4] = {0.f, 0.f, 0.f, 0.f};
  #pragma unroll 4
  for (int c = 0; c < 4; ++c) {
    if (c >= nch) continue;
    float2 ml = mlp[(size_t)c * MLSTR + r];
    float wg = exp2f(ml.x - M);
    den += ml.y * wg;
    union { uint16_t u[4]; uint64_t q; } o;
    o.q = *(const uint64_t*)(Op + (size_t)c * OPSTR + (size_t)r * 64 + d0);
    #pragma unroll
    for (int j = 0; j < 4; ++j) acc[j] += b2f(o.u[j]) * wg;
  }
  float inv = 1.0f / den;
  union { uint16_t u[4]; uint64_t q; } oo;
  #pragma unroll
  for (int j = 0; j < 4; ++j) oo.u[j] = f2b(acc[j] * inv);
  int bb = bh / NH, hh = bh - bb * NH;
  *(uint64_t*)(Ob + (size_t)(bb * S_ + s) * HID + hh * HD + d0) = oo.q;
}

// ---------------- launch ----------------
extern "C" void kernel_launch(void* const* d_in, const int* in_sizes, int n_in,
                              void* d_out, int out_size, void* d_ws, size_t ws_size,
                              hipStream_t stream) {
  (void)in_sizes; (void)n_in; (void)out_size; (void)ws_size;
  const float* X  = (const float*)d_in[0];
  // d_in[1] = attention_mask: pure causal tril, applied analytically in attn_kernel
  const float* Wq = (const float*)d_in[2];
  const float* bq = (const float*)d_in[3];
  const float* Wk = (const float*)d_in[4];
  const float* bk = (const float*)d_in[5];
  const float* Wv = (const float*)d_in[6];
  const float* bv = (const float*)d_in[7];
  const float* Wo = (const float*)d_in[8];
  const int* pos  = (const int*)d_in[9];

  char* p = (char*)d_ws;
  auto carve = [&](size_t n) -> char* { char* r = p; p += (n + 255) & ~(size_t)255; return r; };

  uint16_t* Xb    = (uint16_t*)carve((size_t)MROWS * HID * 2);
  uint16_t* WqkvT = (uint16_t*)carve((size_t)NQKV * 896 * 2);
  uint16_t* WoT   = (uint16_t*)carve((size_t)896 * 896 * 2);
  float*    bqkv  = (float*)carve((size_t)NQKV * 4);
  float*    cosT  = (float*)carve((size_t)S_ * 32 * 4);
  float*    sinT  = (float*)carve((size_t)S_ * 32 * 4);
  uint16_t* Qb    = (uint16_t*)carve((size_t)MROWS * HID * 2);
  uint16_t* Kb    = (uint16_t*)carve((size_t)MROWS * 128 * 2);
  uint16_t* Vf    = (uint16_t*)carve((size_t)MROWS * 128 * 2);
  uint16_t* Vt    = (uint16_t*)carve((size_t)MROWS * 128 * 2);
  uint16_t* Op    = (uint16_t*)carve((size_t)OPSTR * 4 * 2);
  float2*   mlp   = (float2*)carve((size_t)MLSTR * 4 * 8);
  uint16_t* Ob    = Xb;   // Xb dead after QKV gemm; attn/combine write Ob afterwards

  cvt_x_kernel<<<dim3((MROWS * HID / 4) / 256), 256, 0, stream>>>(X, Xb);
  pack_all_kernel<<<dim3(1797), dim3(32, 8), 0, stream>>>(Wq, Wk, Wv, Wo, bq, bk, bv,
                                                          WqkvT, WoT, bqkv);
  rope_table_kernel<<<dim3(S_ * 32 / 256), 256, 0, stream>>>(pos, cosT, sinT);

  gemm_bt_kernel<1><<<dim3(MROWS / 128, NQKV / 64), 256, 0, stream>>>(
      Xb, WqkvT, bqkv, nullptr, NQKV, 896, cosT, sinT, Qb, Kb, Vf);

  packv_kernel<<<dim3(S_ / 64, BATCH * NKV), 256, 0, stream>>>(Vf, Vt);

  attn_kernel<<<dim3(320, NKV * BATCH), 448, 0, stream>>>(Qb, Kb, Vt, Ob, Op, mlp);
  combine_kernel<<<dim3(BATCH * NH * SROWS * 16 / 256), 256, 0, stream>>>(Op, mlp, Ob);

  gemm_bt_kernel<0><<<dim3(MROWS / 128, 896 / 64), 256, 0, stream>>>(
      Ob, WoT, nullptr, d_out, 896, 896, nullptr, nullptr, nullptr, nullptr, nullptr);
}

// Round 11
// 99.627 us; speedup vs baseline: 1.5415x; 1.0497x over previous
//
#include <hip/hip_runtime.h>
#include <stdint.h>

#define DEV __device__ __forceinline__

using bf16x8 = __attribute__((ext_vector_type(8))) short;
using f32x4  = __attribute__((ext_vector_type(4))) float;

DEV float b2f(uint16_t h){ return __uint_as_float(((uint32_t)h)<<16); }
DEV uint16_t f2b(float f){ uint32_t u=__float_as_uint(f); u += 0x7fffu + ((u>>16)&1u); return (uint16_t)(u>>16); }
// pack two f32 -> (bf16(a) | bf16(b)<<16), truncating round (1 v_perm_b32)
DEV uint32_t pk2(float a, float b){
  return __builtin_amdgcn_perm(__float_as_uint(b), __float_as_uint(a), 0x07060302u);
}

// async global->LDS, 16B per lane; LDS dest must be wave-uniform base + lane*16
#define GLOAD16(gp, lp) __builtin_amdgcn_global_load_lds( \
    (__attribute__((address_space(1))) void*)(gp), \
    (__attribute__((address_space(3))) void*)(lp), 16, 0, 0)

constexpr int S_    = 2048;
constexpr int HID   = 896;
constexpr int NH    = 14;
constexpr int NKV   = 2;
constexpr int HD    = 64;
constexpr int BATCH = 2;
constexpr int MROWS = BATCH * S_;   // 4096
constexpr int NQKV  = 1152;         // 896 + 128 + 128
constexpr int SROWS = 1536;         // rows s in [512,2048) have split partials
constexpr int OPSTR = BATCH * NH * SROWS * 64;   // elements per partial slot
constexpr int MLSTR = BATCH * NH * SROWS;        // float2 per partial slot
// log2(e) folded into Q scale: scores in log2-domain, exp -> native exp2
constexpr float QSCALE = 0.125f * 1.4426950408889634f;

// ---- merged prep: weight pack (0..1791) | cvt_x (1792..5375) | rope (5376..5631) | bias (5632..5636)
__global__ void prep_all_kernel(const float* __restrict__ X,
                                const float* __restrict__ Wq, const float* __restrict__ Wk,
                                const float* __restrict__ Wv, const float* __restrict__ Wo,
                                const float* __restrict__ bq, const float* __restrict__ bk,
                                const float* __restrict__ bv, const int* __restrict__ pos0,
                                uint16_t* __restrict__ Xb,
                                uint16_t* __restrict__ WqkvT, uint16_t* __restrict__ WoT,
                                float* __restrict__ bqkv,
                                float* __restrict__ cosT, float* __restrict__ sinT) {
  const int blk = blockIdx.x, tid = threadIdx.x;
  if (blk < 1792) {                                // weight pack (32x32 tile transpose)
    const int lx = tid & 31, ly = tid >> 5;        // 32 x 8
    const float* src; uint16_t* dst; int ncols, rowOff, i;
    if (blk < 784)       { src = Wq; dst = WqkvT; ncols = 896; rowOff = 0;    i = blk;       }
    else if (blk < 896)  { src = Wk; dst = WqkvT; ncols = 128; rowOff = 896;  i = blk - 784; }
    else if (blk < 1008) { src = Wv; dst = WqkvT; ncols = 128; rowOff = 1024; i = blk - 896; }
    else                 { src = Wo; dst = WoT;   ncols = 896; rowOff = 0;    i = blk - 1008;}
    const int nb = ncols >> 5;
    const int n0 = (i % nb) * 32, k0 = (i / nb) * 32;
    __shared__ uint16_t tile[32][33];
    #pragma unroll
    for (int r = 0; r < 32; r += 8)
      tile[ly + r][lx] = f2b(src[(size_t)(k0 + ly + r) * ncols + (n0 + lx)]);
    __syncthreads();
    #pragma unroll
    for (int r = 0; r < 32; r += 8)
      dst[(size_t)(rowOff + n0 + ly + r) * 896 + (k0 + lx)] = tile[lx][ly + r];
  } else if (blk < 5376) {                         // cvt_x: f32 -> bf16, 4/thread
    int i = (blk - 1792) * 256 + tid;
    float4 v = ((const float4*)X)[i];
    union { uint16_t u[4]; uint64_t q; } r;
    r.u[0] = f2b(v.x); r.u[1] = f2b(v.y); r.u[2] = f2b(v.z); r.u[3] = f2b(v.w);
    ((uint64_t*)Xb)[i] = r.q;
  } else if (blk < 5632) {                         // rope table
    int idx = (blk - 5376) * 256 + tid;            // S*32
    int s = idx >> 5, j = idx & 31;
    float inv = exp2f(-(float)j * (19.931568569324174f / 32.0f));  // 1e6^(-j/32)
    float ang = (float)(pos0[0] + s) * inv;
    float sv, cv;
    sincosf(ang, &sv, &cv);
    cosT[idx] = cv; sinT[idx] = sv;
  } else {                                         // bias concat
    int i = (blk - 5632) * 256 + tid;
    if (i < NQKV) bqkv[i] = i < 896 ? bq[i] : (i < 1024 ? bk[i - 896] : bv[i - 1024]);
  }
}

// ---------------- V: Vf (B,S,128) -> V^T (B,KV,D,S), LDS tile transpose ----------------
__global__ void packv_kernel(const uint16_t* __restrict__ Vf, uint16_t* __restrict__ Vt) {
  __shared__ uint16_t tile[64][65];
  const int s0 = blockIdx.x * 64;
  const int g  = blockIdx.y;                  // b*NKV + kv
  const int b = g >> 1, kv = g & 1;
  const int lx = threadIdx.x & 63, ly = threadIdx.x >> 6;   // 64 x 4
  #pragma unroll
  for (int i = 0; i < 64; i += 4)
    tile[ly + i][lx] = Vf[(size_t)(b * S_ + s0 + ly + i) * 128 + kv * 64 + lx];
  __syncthreads();
  #pragma unroll
  for (int i = 0; i < 64; i += 4)
    Vt[((size_t)g * HD + ly + i) * S_ + s0 + lx] = tile[lx][ly + i];
}

// ---------------- GEMM: C(MxN) = A(MxK,bf16) * Bt(NxK,bf16)^T + bias ----------------
// Tile 128x64, 4 waves of 32x64 (acc[2][4]). EPI 0: f32 C. EPI 1: fused QKV->RoPE.
template <int EPI>
__global__ __launch_bounds__(256) void gemm_bt_kernel(
    const uint16_t* __restrict__ A, const uint16_t* __restrict__ Bt,
    const float* __restrict__ bias, void* __restrict__ Cv, int N, int K,
    const float* __restrict__ cosT, const float* __restrict__ sinT,
    uint16_t* __restrict__ Qb, uint16_t* __restrict__ Kb, uint16_t* __restrict__ Vf) {
  __shared__ __align__(16) uint16_t As[128 * 64];   // 16 KB
  __shared__ __align__(16) uint16_t Bs[64 * 64];    // 8 KB
  const int tid = threadIdx.x;
  const int l = tid & 63, w = tid >> 6;
  const int m0 = blockIdx.x * 128, n0 = blockIdx.y * 64;
  const int wr = w * 32;                            // 32 rows per wave, all 64 cols

  f32x4 acc[2][4] = {};
  for (int k0 = 0; k0 < K; k0 += 64) {
    #pragma unroll
    for (int i = 0; i < 4; ++i) {
      int cid = i * 256 + tid;                 // 1024 A-chunks
      int row = cid >> 3;
      int sch = (cid & 7) ^ (row & 7);
      GLOAD16(A + (size_t)(m0 + row) * K + (k0 + sch * 8), (char*)As + cid * 16);
    }
    #pragma unroll
    for (int i = 0; i < 2; ++i) {
      int cid = i * 256 + tid;                 // 512 B-chunks
      int row = cid >> 3;
      int sch = (cid & 7) ^ (row & 7);
      GLOAD16(Bt + (size_t)(n0 + row) * K + (k0 + sch * 8), (char*)Bs + cid * 16);
    }
    __syncthreads();
    __builtin_amdgcn_s_setprio(1);
    #pragma unroll
    for (int ks = 0; ks < 2; ++ks) {
      bf16x8 af[2], bfr[4];
      #pragma unroll
      for (int mi = 0; mi < 2; ++mi) {
        int row = wr + mi * 16 + (l & 15);
        int ch = ((l >> 4) + ks * 4) ^ (row & 7);
        af[mi] = *(const bf16x8*)((const char*)As + row * 128 + ch * 16);
      }
      #pragma unroll
      for (int ni = 0; ni < 4; ++ni) {
        int row = ni * 16 + (l & 15);
        int ch = ((l >> 4) + ks * 4) ^ (row & 7);
        bfr[ni] = *(const bf16x8*)((const char*)Bs + row * 128 + ch * 16);
      }
      #pragma unroll
      for (int mi = 0; mi < 2; ++mi)
        #pragma unroll
        for (int ni = 0; ni < 4; ++ni)
          acc[mi][ni] = __builtin_amdgcn_mfma_f32_16x16x32_bf16(af[mi], bfr[ni], acc[mi][ni], 0, 0, 0);
    }
    __builtin_amdgcn_s_setprio(0);
    __syncthreads();
  }

  const int tc = l & 15, g = l >> 4;
  if (EPI == 1) {
    if (n0 < 896) {
      // Q head h = n0>>6: RoPE pairs (ni, ni+2), scale QSCALE (1/8 * log2e)
      #pragma unroll
      for (int mi = 0; mi < 2; ++mi) {
        #pragma unroll
        for (int jr = 0; jr < 4; ++jr) {
          int row = m0 + wr + mi * 16 + g * 4 + jr;
          int bb = row >> 11, s = row & (S_ - 1);
          const float* cp = cosT + s * 32;
          const float* sp = sinT + s * 32;
          #pragma unroll
          for (int ni = 0; ni < 2; ++ni) {
            int col = n0 + ni * 16 + tc;
            int j = col & 63;   // < 32
            float c = cp[j], sn = sp[j];
            float alo = acc[mi][ni][jr] + bias[col];
            float ahi = acc[mi][ni + 2][jr] + bias[col + 32];
            size_t dst = ((size_t)(bb * NH + (n0 >> 6)) * S_ + s) * HD + j;
            Qb[dst]      = f2b((alo * c - ahi * sn) * QSCALE);
            Qb[dst + 32] = f2b((ahi * c + alo * sn) * QSCALE);
          }
        }
      }
    } else if (n0 < 1024) {
      // K head kvh = (n0-896)>>6: RoPE, no scale
      #pragma unroll
      for (int mi = 0; mi < 2; ++mi) {
        #pragma unroll
        for (int jr = 0; jr < 4; ++jr) {
          int row = m0 + wr + mi * 16 + g * 4 + jr;
          int bb = row >> 11, s = row & (S_ - 1);
          const float* cp = cosT + s * 32;
          const float* sp = sinT + s * 32;
          #pragma unroll
          for (int ni = 0; ni < 2; ++ni) {
            int col = n0 + ni * 16 + tc;
            int j = col & 63;   // < 32
            float c = cp[j], sn = sp[j];
            float alo = acc[mi][ni][jr] + bias[col];
            float ahi = acc[mi][ni + 2][jr] + bias[col + 32];
            size_t dst = ((size_t)(bb * NKV + ((n0 - 896) >> 6)) * S_ + s) * HD + j;
            Kb[dst]      = f2b(alo * c - ahi * sn);
            Kb[dst + 32] = f2b(ahi * c + alo * sn);
          }
        }
      }
    } else {
      // V block: plain bf16, row-major Vf (B*S, 128)
      #pragma unroll
      for (int mi = 0; mi < 2; ++mi)
        #pragma unroll
        for (int ni = 0; ni < 4; ++ni) {
          int col = n0 + ni * 16 + tc;
          #pragma unroll
          for (int jr = 0; jr < 4; ++jr) {
            int row = m0 + wr + mi * 16 + g * 4 + jr;
            Vf[(size_t)row * 128 + (col - 1024)] = f2b(acc[mi][ni][jr] + bias[col]);
          }
        }
    }
  } else {
    #pragma unroll
    for (int mi = 0; mi < 2; ++mi) {
      #pragma unroll
      for (int ni = 0; ni < 4; ++ni) {
        int col = n0 + ni * 16 + tc;
        #pragma unroll
        for (int j = 0; j < 4; ++j) {
          int row = m0 + wr + mi * 16 + g * 4 + j;
          ((float*)Cv)[(size_t)row * N + col] = acc[mi][ni][j];
        }
      }
    }
  }
}

// ---------------- Flash attention v11: R7 structure + exp2 (LPT reverted) ----------------
// Block = 448 threads, wave w = head kv*7+w, shared K/V LDS tile, depth-1 prefetch.
// Softmax in exp2 domain (Q pre-scaled by log2e/8), defer-max THR = 11.5.
__global__ __launch_bounds__(448) void attn_kernel(
    const uint16_t* __restrict__ Qb, const uint16_t* __restrict__ Kb,
    const uint16_t* __restrict__ Vt, uint16_t* __restrict__ Ob,
    uint16_t* __restrict__ Op, float2* __restrict__ mlp) {
  __shared__ __align__(16) uint16_t Ks[2][64 * 64];   // [kv][d], swizzled
  __shared__ __align__(16) uint16_t Vs[2][64 * 64];   // [d][kv], swizzled
  const int tid = threadIdx.x, l = tid & 63, w = tid >> 6;
  const int u = blockIdx.x;                   // natural order (R7-validated)
  const int kv = blockIdx.y & 1, b = blockIdx.y >> 1;
  const int tc = l & 15, g = l >> 4;
  const int srcA = (((2 * g) & 3) << 4) | tc;
  const int srcB = (((2 * g + 1) & 3) << 4) | tc;

  // decode (qt16, ck)
  int qt16, ck;
  if (u < 32)       { qt16 = u;                   ck = 0; }
  else if (u < 96)  { int i = u - 32;  qt16 = 32 + (i >> 1); ck = i & 1; }
  else if (u < 192) { int i = u - 96;  int q3 = i / 3; qt16 = 64 + q3; ck = i - 3 * q3; }
  else              { int i = u - 192; qt16 = 96 + (i >> 2); ck = i & 3; }
  const int ntiles = (qt16 >> 2) + 1;
  const int nch    = (qt16 >> 5) + 1;
  const int tlo    = 8 * ck;
  const int thi    = (8 * ck + 8 < ntiles) ? (8 * ck + 8) : ntiles;
  const int ns     = thi - tlo;
  const bool dodiag = (ck == nch - 1);
  const bool split  = (nch > 1);

  const int h  = kv * 7 + w;
  const int qg = qt16 * 16 + tc;

  const uint16_t* Khead = Kb + (size_t)(b * NKV + kv) * S_ * HD;
  const uint16_t* Vhead = Vt + (size_t)(b * NKV + kv) * HD * S_;

  // 64x64 bf16 tile = 512 x 16B chunks: 448 lanes + wave0 covers 448..511.
  auto stage = [&](int t, int bi) {
    const int t0 = t * 64;
    #pragma unroll
    for (int i = 0; i < 2; ++i) {
      if (i == 0 || tid < 64) {                 // wave-uniform predicate
        int cid = i * 448 + tid;                // 0..511
        int row = cid >> 3, sch = (cid & 7) ^ (row & 7);
        GLOAD16(Khead + (size_t)(t0 + row) * HD + sch * 8, (char*)Ks[bi] + cid * 16);
        GLOAD16(Vhead + (size_t)row * S_ + t0 + sch * 8,   (char*)Vs[bi] + cid * 16);
      }
    }
  };

  // Q fragments (pre-scaled by QSCALE): lane owns one q-row (qg), d-slice g*8
  const uint16_t* qptr = Qb + ((size_t)(b * NH + h) * S_ + qg) * HD + g * 8;
  bf16x8 qf0 = *(const bf16x8*)qptr;
  bf16x8 qf1 = *(const bf16x8*)(qptr + 32);

  f32x4 oacc[4] = {};
  float mrow = -1e30f, lrow = 0.f;   // lane-partial over its 16 kv slots

  stage(tlo, 0);

  #pragma unroll 1
  for (int i = 0; i < ns; ++i) {
    const int t = tlo + i;
    asm volatile("s_waitcnt vmcnt(0)" ::: "memory");
    __builtin_amdgcn_s_barrier();
    if (i + 1 < ns) stage(t + 1, (i + 1) & 1);

    const uint16_t* Kc = Ks[i & 1];
    const uint16_t* Vc = Vs[i & 1];
    const int t0 = t * 64;

    // S^T = K * Q^T : sacc[c][r] = S[kv = t0 + c*16 + g*4 + r][q = qg]
    f32x4 sacc[4] = {};
    __builtin_amdgcn_s_setprio(1);
    #pragma unroll
    for (int ks = 0; ks < 2; ++ks) {
      bf16x8 qf = ks ? qf1 : qf0;
      #pragma unroll
      for (int c = 0; c < 4; ++c) {
        int trow = c * 16 + tc;
        int ch = (g + ks * 4) ^ (tc & 7);
        bf16x8 kf = *(const bf16x8*)((const char*)Kc + trow * 128 + ch * 16);
        sacc[c] = __builtin_amdgcn_mfma_f32_16x16x32_bf16(kf, qf, sacc[c], 0, 0, 0);
      }
    }
    __builtin_amdgcn_s_setprio(0);

    // causal mask on diagonal tile only
    if (dodiag && t == ntiles - 1) {
      #pragma unroll
      for (int c = 0; c < 4; ++c) {
        int kvb = t0 + c * 16 + g * 4;
        #pragma unroll
        for (int r = 0; r < 4; ++r)
          if (kvb + r > qg) sacc[c][r] = -1e30f;
      }
    }

    // T13 defer-max (exp2 domain, THR = 8*log2e ~ 11.5)
    float pmax = sacc[0][0];
    #pragma unroll
    for (int c = 0; c < 4; ++c)
      #pragma unroll
      for (int r = 0; r < 4; ++r) pmax = fmaxf(pmax, sacc[c][r]);
    if (__any(pmax > mrow + 11.5f)) {
      float mt = fmaxf(pmax, __shfl_xor(pmax, 16));
      mt = fmaxf(mt, __shfl_xor(mt, 32));
      float mn = fmaxf(mrow, mt);
      float corr = exp2f(mrow - mn);
      mrow = mn;
      lrow *= corr;
      #pragma unroll
      for (int dt = 0; dt < 4; ++dt) oacc[dt] *= corr;
    }
    float rs = 0.f;
    #pragma unroll
    for (int c = 0; c < 4; ++c)
      #pragma unroll
      for (int r = 0; r < 4; ++r) {
        float e = exp2f(sacc[c][r] - mrow);
        sacc[c][r] = e; rs += e;
      }
    lrow += rs;

    // pack P to bf16 words and redistribute into PV B-fragments
    uint32_t w0[4], w1[4];
    #pragma unroll
    for (int c = 0; c < 4; ++c) {
      w0[c] = pk2(sacc[c][0], sacc[c][1]);
      w1[c] = pk2(sacc[c][2], sacc[c][3]);
    }
    const bool lo = g < 2;
    bf16x8 pf[2];
    {
      union { uint32_t u[4]; bf16x8 v; } p0, p1;
      uint32_t a0 = __shfl((int)w0[0], srcA), a1 = __shfl((int)w1[0], srcA);
      uint32_t a2 = __shfl((int)w0[0], srcB), a3 = __shfl((int)w1[0], srcB);
      uint32_t b0 = __shfl((int)w0[1], srcA), b1 = __shfl((int)w1[1], srcA);
      uint32_t b2 = __shfl((int)w0[1], srcB), b3 = __shfl((int)w1[1], srcB);
      p0.u[0] = lo ? a0 : b0; p0.u[1] = lo ? a1 : b1;
      p0.u[2] = lo ? a2 : b2; p0.u[3] = lo ? a3 : b3;
      pf[0] = p0.v;
      uint32_t c0 = __shfl((int)w0[2], srcA), c1 = __shfl((int)w1[2], srcA);
      uint32_t c2 = __shfl((int)w0[2], srcB), c3 = __shfl((int)w1[2], srcB);
      uint32_t d0 = __shfl((int)w0[3], srcA), d1 = __shfl((int)w1[3], srcA);
      uint32_t d2 = __shfl((int)w0[3], srcB), d3 = __shfl((int)w1[3], srcB);
      p1.u[0] = lo ? c0 : d0; p1.u[1] = lo ? c1 : d1;
      p1.u[2] = lo ? c2 : d2; p1.u[3] = lo ? c3 : d3;
      pf[1] = p1.v;
    }

    // O^T += V^T * P^T
    __builtin_amdgcn_s_setprio(1);
    #pragma unroll
    for (int ks = 0; ks < 2; ++ks) {
      #pragma unroll
      for (int dt = 0; dt < 4; ++dt) {
        int drow = dt * 16 + tc;
        int vch = (g + ks * 4) ^ (tc & 7);
        bf16x8 vf = *(const bf16x8*)((const char*)Vc + drow * 128 + vch * 16);
        oacc[dt] = __builtin_amdgcn_mfma_f32_16x16x32_bf16(vf, pf[ks], oacc[dt], 0, 0, 0);
      }
    }
    __builtin_amdgcn_s_setprio(0);
  }

  // combine lane-partial lrow across the 4 lane-groups
  float ltot = lrow;
  ltot += __shfl_xor(ltot, 16);
  ltot += __shfl_xor(ltot, 32);

  if (!split) {
    float inv = 1.0f / ltot;
    size_t obase = (size_t)(b * S_ + qg) * HID + h * HD;
    #pragma unroll
    for (int dt = 0; dt < 4; ++dt) {
      union { uint16_t u[4]; uint64_t q; } o;
      #pragma unroll
      for (int r = 0; r < 4; ++r) o.u[r] = f2b(oacc[dt][r] * inv);
      *(uint64_t*)(Ob + obase + dt * 16 + g * 4) = o.q;
    }
  } else {
    // partial slot ck: unnormalized bf16 O + (m, l)  [m in log2 domain]
    size_t rowid = (size_t)(b * NH + h) * SROWS + (qg - 512);
    uint16_t* Opc = Op + (size_t)ck * OPSTR + rowid * 64;
    #pragma unroll
    for (int dt = 0; dt < 4; ++dt) {
      union { uint16_t u[4]; uint64_t q; } o;
      #pragma unroll
      for (int r = 0; r < 4; ++r) o.u[r] = f2b(oacc[dt][r]);
      *(uint64_t*)(Opc + dt * 16 + g * 4) = o.q;
    }
    if (g == 0) mlp[(size_t)ck * MLSTR + rowid] = make_float2(mrow, ltot);
  }
}

// ---------------- combine up to 4 partials for rows s >= 512 (exp2 domain) ----------------
__global__ void combine_kernel(const uint16_t* __restrict__ Op, const float2* __restrict__ mlp,
                               uint16_t* __restrict__ Ob) {
  int idx = blockIdx.x * 256 + threadIdx.x;   // B*NH*SROWS*16
  int r = idx >> 4;                           // (b*NH+h)*SROWS + (s-512)
  int d0 = (idx & 15) * 4;
  int bh = r / SROWS;
  int sr = r - bh * SROWS;
  int s = 512 + sr;
  int nch = (s >> 9) + 1;                     // 2..4
  float M = -1e30f;
  #pragma unroll 4
  for (int c = 0; c < 4; ++c)
    if (c < nch) M = fmaxf(M, mlp[(size_t)c * MLSTR + r].x);
  float den = 0.f, acc[4] = {0.f, 0.f, 0.f, 0.f};
  #pragma unroll 4
  for (int c = 0; c < 4; ++c) {
    if (c >= nch) continue;
    float2 ml = mlp[(size_t)c * MLSTR + r];
    float wg = exp2f(ml.x - M);
    den += ml.y * wg;
    union { uint16_t u[4]; uint64_t q; } o;
    o.q = *(const uint64_t*)(Op + (size_t)c * OPSTR + (size_t)r * 64 + d0);
    #pragma unroll
    for (int j = 0; j < 4; ++j) acc[j] += b2f(o.u[j]) * wg;
  }
  float inv = 1.0f / den;
  union { uint16_t u[4]; uint64_t q; } oo;
  #pragma unroll
  for (int j = 0; j < 4; ++j) oo.u[j] = f2b(acc[j] * inv);
  int bb = bh / NH, hh = bh - bb * NH;
  *(uint64_t*)(Ob + (size_t)(bb * S_ + s) * HID + hh * HD + d0) = oo.q;
}

// ---------------- launch ----------------
extern "C" void kernel_launch(void* const* d_in, const int* in_sizes, int n_in,
                              void* d_out, int out_size, void* d_ws, size_t ws_size,
                              hipStream_t stream) {
  (void)in_sizes; (void)n_in; (void)out_size; (void)ws_size;
  const float* X  = (const float*)d_in[0];
  // d_in[1] = attention_mask: pure causal tril, applied analytically in attn_kernel
  const float* Wq = (const float*)d_in[2];
  const float* bq = (const float*)d_in[3];
  const float* Wk = (const float*)d_in[4];
  const float* bk = (const float*)d_in[5];
  const float* Wv = (const float*)d_in[6];
  const float* bv = (const float*)d_in[7];
  const float* Wo = (const float*)d_in[8];
  const int* pos  = (const int*)d_in[9];

  char* p = (char*)d_ws;
  auto carve = [&](size_t n) -> char* { char* r = p; p += (n + 255) & ~(size_t)255; return r; };

  uint16_t* Xb    = (uint16_t*)carve((size_t)MROWS * HID * 2);
  uint16_t* WqkvT = (uint16_t*)carve((size_t)NQKV * 896 * 2);
  uint16_t* WoT   = (uint16_t*)carve((size_t)896 * 896 * 2);
  float*    bqkv  = (float*)carve((size_t)NQKV * 4);
  float*    cosT  = (float*)carve((size_t)S_ * 32 * 4);
  float*    sinT  = (float*)carve((size_t)S_ * 32 * 4);
  uint16_t* Qb    = (uint16_t*)carve((size_t)MROWS * HID * 2);
  uint16_t* Kb    = (uint16_t*)carve((size_t)MROWS * 128 * 2);
  uint16_t* Vf    = (uint16_t*)carve((size_t)MROWS * 128 * 2);
  uint16_t* Vt    = (uint16_t*)carve((size_t)MROWS * 128 * 2);
  uint16_t* Op    = (uint16_t*)carve((size_t)OPSTR * 4 * 2);
  float2*   mlp   = (float2*)carve((size_t)MLSTR * 4 * 8);
  uint16_t* Ob    = Xb;   // Xb dead after QKV gemm; attn/combine write Ob afterwards

  prep_all_kernel<<<dim3(5637), 256, 0, stream>>>(X, Wq, Wk, Wv, Wo, bq, bk, bv, pos,
                                                  Xb, WqkvT, WoT, bqkv, cosT, sinT);

  gemm_bt_kernel<1><<<dim3(MROWS / 128, NQKV / 64), 256, 0, stream>>>(
      Xb, WqkvT, bqkv, nullptr, NQKV, 896, cosT, sinT, Qb, Kb, Vf);

  packv_kernel<<<dim3(S_ / 64, BATCH * NKV), 256, 0, stream>>>(Vf, Vt);

  attn_kernel<<<dim3(320, NKV * BATCH), 448, 0, stream>>>(Qb, Kb, Vt, Ob, Op, mlp);
  combine_kernel<<<dim3(BATCH * NH * SROWS * 16 / 256), 256, 0, stream>>>(Op, mlp, Ob);

  gemm_bt_kernel<0><<<dim3(MROWS / 128, 896 / 64), 256, 0, stream>>>(
      Ob, WoT, nullptr, d_out, 896, 896, nullptr, nullptr, nullptr, nullptr, nullptr);
}

// Round 12
// 93.910 us; speedup vs baseline: 1.6354x; 1.0609x over previous
//
#include <hip/hip_runtime.h>
#include <stdint.h>

#define DEV __device__ __forceinline__

using bf16x8 = __attribute__((ext_vector_type(8))) short;
using f32x4  = __attribute__((ext_vector_type(4))) float;

DEV float b2f(uint16_t h){ return __uint_as_float(((uint32_t)h)<<16); }
DEV uint16_t f2b(float f){ uint32_t u=__float_as_uint(f); u += 0x7fffu + ((u>>16)&1u); return (uint16_t)(u>>16); }
// pack two f32 -> (bf16(a) | bf16(b)<<16), truncating round (1 v_perm_b32)
DEV uint32_t pk2(float a, float b){
  return __builtin_amdgcn_perm(__float_as_uint(b), __float_as_uint(a), 0x07060302u);
}
// native hardware exp2 (v_exp_f32 IS base-2): avoids libm exp2f's denormal-safe
// expansion (range check + scale + select) that cost +4.7us in R11.
DEV float fexp2(float x){ float r; asm("v_exp_f32 %0, %1" : "=v"(r) : "v"(x)); return r; }

// async global->LDS, 16B per lane; LDS dest must be wave-uniform base + lane*16
#define GLOAD16(gp, lp) __builtin_amdgcn_global_load_lds( \
    (__attribute__((address_space(1))) void*)(gp), \
    (__attribute__((address_space(3))) void*)(lp), 16, 0, 0)

constexpr int S_    = 2048;
constexpr int HID   = 896;
constexpr int NH    = 14;
constexpr int NKV   = 2;
constexpr int HD    = 64;
constexpr int BATCH = 2;
constexpr int MROWS = BATCH * S_;   // 4096
constexpr int NQKV  = 1152;         // 896 + 128 + 128
constexpr int SROWS = 1536;         // rows s in [512,2048) have split partials
constexpr int OPSTR = BATCH * NH * SROWS * 64;   // elements per partial slot
constexpr int MLSTR = BATCH * NH * SROWS;        // float2 per partial slot
// log2(e) folded into Q scale: scores in log2-domain, exp -> native exp2
constexpr float QSCALE = 0.125f * 1.4426950408889634f;

// ---- merged prep: weight pack (0..1791) | cvt_x (1792..5375) | rope (5376..5631) | bias (5632..5636)
__global__ void prep_all_kernel(const float* __restrict__ X,
                                const float* __restrict__ Wq, const float* __restrict__ Wk,
                                const float* __restrict__ Wv, const float* __restrict__ Wo,
                                const float* __restrict__ bq, const float* __restrict__ bk,
                                const float* __restrict__ bv, const int* __restrict__ pos0,
                                uint16_t* __restrict__ Xb,
                                uint16_t* __restrict__ WqkvT, uint16_t* __restrict__ WoT,
                                float* __restrict__ bqkv,
                                float* __restrict__ cosT, float* __restrict__ sinT) {
  const int blk = blockIdx.x, tid = threadIdx.x;
  if (blk < 1792) {                                // weight pack (32x32 tile transpose)
    const int lx = tid & 31, ly = tid >> 5;        // 32 x 8
    const float* src; uint16_t* dst; int ncols, rowOff, i;
    if (blk < 784)       { src = Wq; dst = WqkvT; ncols = 896; rowOff = 0;    i = blk;       }
    else if (blk < 896)  { src = Wk; dst = WqkvT; ncols = 128; rowOff = 896;  i = blk - 784; }
    else if (blk < 1008) { src = Wv; dst = WqkvT; ncols = 128; rowOff = 1024; i = blk - 896; }
    else                 { src = Wo; dst = WoT;   ncols = 896; rowOff = 0;    i = blk - 1008;}
    const int nb = ncols >> 5;
    const int n0 = (i % nb) * 32, k0 = (i / nb) * 32;
    __shared__ uint16_t tile[32][33];
    #pragma unroll
    for (int r = 0; r < 32; r += 8)
      tile[ly + r][lx] = f2b(src[(size_t)(k0 + ly + r) * ncols + (n0 + lx)]);
    __syncthreads();
    #pragma unroll
    for (int r = 0; r < 32; r += 8)
      dst[(size_t)(rowOff + n0 + ly + r) * 896 + (k0 + lx)] = tile[lx][ly + r];
  } else if (blk < 5376) {                         // cvt_x: f32 -> bf16, 4/thread
    int i = (blk - 1792) * 256 + tid;
    float4 v = ((const float4*)X)[i];
    union { uint16_t u[4]; uint64_t q; } r;
    r.u[0] = f2b(v.x); r.u[1] = f2b(v.y); r.u[2] = f2b(v.z); r.u[3] = f2b(v.w);
    ((uint64_t*)Xb)[i] = r.q;
  } else if (blk < 5632) {                         // rope table
    int idx = (blk - 5376) * 256 + tid;            // S*32
    int s = idx >> 5, j = idx & 31;
    float inv = exp2f(-(float)j * (19.931568569324174f / 32.0f));  // 1e6^(-j/32)
    float ang = (float)(pos0[0] + s) * inv;
    float sv, cv;
    sincosf(ang, &sv, &cv);
    cosT[idx] = cv; sinT[idx] = sv;
  } else {                                         // bias concat
    int i = (blk - 5632) * 256 + tid;
    if (i < NQKV) bqkv[i] = i < 896 ? bq[i] : (i < 1024 ? bk[i - 896] : bv[i - 1024]);
  }
}

// ---------------- V: Vf (B,S,128) -> V^T (B,KV,D,S), LDS tile transpose ----------------
__global__ void packv_kernel(const uint16_t* __restrict__ Vf, uint16_t* __restrict__ Vt) {
  __shared__ uint16_t tile[64][65];
  const int s0 = blockIdx.x * 64;
  const int g  = blockIdx.y;                  // b*NKV + kv
  const int b = g >> 1, kv = g & 1;
  const int lx = threadIdx.x & 63, ly = threadIdx.x >> 6;   // 64 x 4
  #pragma unroll
  for (int i = 0; i < 64; i += 4)
    tile[ly + i][lx] = Vf[(size_t)(b * S_ + s0 + ly + i) * 128 + kv * 64 + lx];
  __syncthreads();
  #pragma unroll
  for (int i = 0; i < 64; i += 4)
    Vt[((size_t)g * HD + ly + i) * S_ + s0 + lx] = tile[lx][ly + i];
}

// ---------------- GEMM: C(MxN) = A(MxK,bf16) * Bt(NxK,bf16)^T + bias ----------------
// Tile 128x64, 4 waves of 32x64 (acc[2][4]); double-buffered LDS, T3-minimum
// 2-phase pipeline (stage t+1 overlaps compute t). EPI 0: f32 C. EPI 1: QKV->RoPE.
template <int EPI>
__global__ __launch_bounds__(256) void gemm_bt_kernel(
    const uint16_t* __restrict__ A, const uint16_t* __restrict__ Bt,
    const float* __restrict__ bias, void* __restrict__ Cv, int N, int K,
    const float* __restrict__ cosT, const float* __restrict__ sinT,
    uint16_t* __restrict__ Qb, uint16_t* __restrict__ Kb, uint16_t* __restrict__ Vf) {
  __shared__ __align__(16) uint16_t As[2][128 * 64];   // 32 KB
  __shared__ __align__(16) uint16_t Bs[2][64 * 64];    // 16 KB
  const int tid = threadIdx.x;
  const int l = tid & 63, w = tid >> 6;
  const int m0 = blockIdx.x * 128, n0 = blockIdx.y * 64;
  const int wr = w * 32;                            // 32 rows per wave, all 64 cols

  auto stage = [&](int k0, int bi) {
    #pragma unroll
    for (int i = 0; i < 4; ++i) {
      int cid = i * 256 + tid;                 // 1024 A-chunks
      int row = cid >> 3;
      int sch = (cid & 7) ^ (row & 7);
      GLOAD16(A + (size_t)(m0 + row) * K + (k0 + sch * 8), (char*)As[bi] + cid * 16);
    }
    #pragma unroll
    for (int i = 0; i < 2; ++i) {
      int cid = i * 256 + tid;                 // 512 B-chunks
      int row = cid >> 3;
      int sch = (cid & 7) ^ (row & 7);
      GLOAD16(Bt + (size_t)(n0 + row) * K + (k0 + sch * 8), (char*)Bs[bi] + cid * 16);
    }
  };

  const int nk = K >> 6;
  f32x4 acc[2][4] = {};
  stage(0, 0);
  asm volatile("s_waitcnt vmcnt(0)" ::: "memory");
  __builtin_amdgcn_s_barrier();

  #pragma unroll 1
  for (int t = 0; t < nk; ++t) {
    if (t + 1 < nk) stage((t + 1) << 6, (t + 1) & 1);   // overlap with compute
    const uint16_t* Ac = As[t & 1];
    const uint16_t* Bc = Bs[t & 1];
    __builtin_amdgcn_s_setprio(1);
    #pragma unroll
    for (int ks = 0; ks < 2; ++ks) {
      bf16x8 af[2], bfr[4];
      #pragma unroll
      for (int mi = 0; mi < 2; ++mi) {
        int row = wr + mi * 16 + (l & 15);
        int ch = ((l >> 4) + ks * 4) ^ (row & 7);
        af[mi] = *(const bf16x8*)((const char*)Ac + row * 128 + ch * 16);
      }
      #pragma unroll
      for (int ni = 0; ni < 4; ++ni) {
        int row = ni * 16 + (l & 15);
        int ch = ((l >> 4) + ks * 4) ^ (row & 7);
        bfr[ni] = *(const bf16x8*)((const char*)Bc + row * 128 + ch * 16);
      }
      #pragma unroll
      for (int mi = 0; mi < 2; ++mi)
        #pragma unroll
        for (int ni = 0; ni < 4; ++ni)
          acc[mi][ni] = __builtin_amdgcn_mfma_f32_16x16x32_bf16(af[mi], bfr[ni], acc[mi][ni], 0, 0, 0);
    }
    __builtin_amdgcn_s_setprio(0);
    asm volatile("s_waitcnt vmcnt(0)" ::: "memory");   // next tile landed
    __builtin_amdgcn_s_barrier();                      // all waves done with buf[t&1]
  }

  const int tc = l & 15, g = l >> 4;
  if (EPI == 1) {
    if (n0 < 896) {
      // Q head h = n0>>6: RoPE pairs (ni, ni+2), scale QSCALE (1/8 * log2e)
      #pragma unroll
      for (int mi = 0; mi < 2; ++mi) {
        #pragma unroll
        for (int jr = 0; jr < 4; ++jr) {
          int row = m0 + wr + mi * 16 + g * 4 + jr;
          int bb = row >> 11, s = row & (S_ - 1);
          const float* cp = cosT + s * 32;
          const float* sp = sinT + s * 32;
          #pragma unroll
          for (int ni = 0; ni < 2; ++ni) {
            int col = n0 + ni * 16 + tc;
            int j = col & 63;   // < 32
            float c = cp[j], sn = sp[j];
            float alo = acc[mi][ni][jr] + bias[col];
            float ahi = acc[mi][ni + 2][jr] + bias[col + 32];
            size_t dst = ((size_t)(bb * NH + (n0 >> 6)) * S_ + s) * HD + j;
            Qb[dst]      = f2b((alo * c - ahi * sn) * QSCALE);
            Qb[dst + 32] = f2b((ahi * c + alo * sn) * QSCALE);
          }
        }
      }
    } else if (n0 < 1024) {
      // K head kvh = (n0-896)>>6: RoPE, no scale
      #pragma unroll
      for (int mi = 0; mi < 2; ++mi) {
        #pragma unroll
        for (int jr = 0; jr < 4; ++jr) {
          int row = m0 + wr + mi * 16 + g * 4 + jr;
          int bb = row >> 11, s = row & (S_ - 1);
          const float* cp = cosT + s * 32;
          const float* sp = sinT + s * 32;
          #pragma unroll
          for (int ni = 0; ni < 2; ++ni) {
            int col = n0 + ni * 16 + tc;
            int j = col & 63;   // < 32
            float c = cp[j], sn = sp[j];
            float alo = acc[mi][ni][jr] + bias[col];
            float ahi = acc[mi][ni + 2][jr] + bias[col + 32];
            size_t dst = ((size_t)(bb * NKV + ((n0 - 896) >> 6)) * S_ + s) * HD + j;
            Kb[dst]      = f2b(alo * c - ahi * sn);
            Kb[dst + 32] = f2b(ahi * c + alo * sn);
          }
        }
      }
    } else {
      // V block: plain bf16, row-major Vf (B*S, 128)
      #pragma unroll
      for (int mi = 0; mi < 2; ++mi)
        #pragma unroll
        for (int ni = 0; ni < 4; ++ni) {
          int col = n0 + ni * 16 + tc;
          #pragma unroll
          for (int jr = 0; jr < 4; ++jr) {
            int row = m0 + wr + mi * 16 + g * 4 + jr;
            Vf[(size_t)row * 128 + (col - 1024)] = f2b(acc[mi][ni][jr] + bias[col]);
          }
        }
    }
  } else {
    #pragma unroll
    for (int mi = 0; mi < 2; ++mi) {
      #pragma unroll
      for (int ni = 0; ni < 4; ++ni) {
        int col = n0 + ni * 16 + tc;
        #pragma unroll
        for (int j = 0; j < 4; ++j) {
          int row = m0 + wr + mi * 16 + g * 4 + j;
          ((float*)Cv)[(size_t)row * N + col] = acc[mi][ni][j];
        }
      }
    }
  }
}

// ---------------- Flash attention v12: R7 structure + native-exp2 softmax ----------------
// Block = 448 threads, wave w = head kv*7+w, shared K/V LDS tile, depth-1 prefetch.
// Softmax in exp2 domain (Q pre-scaled by log2e/8), native v_exp_f32, THR = 11.5.
__global__ __launch_bounds__(448) void attn_kernel(
    const uint16_t* __restrict__ Qb, const uint16_t* __restrict__ Kb,
    const uint16_t* __restrict__ Vt, uint16_t* __restrict__ Ob,
    uint16_t* __restrict__ Op, float2* __restrict__ mlp) {
  __shared__ __align__(16) uint16_t Ks[2][64 * 64];   // [kv][d], swizzled
  __shared__ __align__(16) uint16_t Vs[2][64 * 64];   // [d][kv], swizzled
  const int tid = threadIdx.x, l = tid & 63, w = tid >> 6;
  const int u = blockIdx.x;                   // natural order (R7-validated)
  const int kv = blockIdx.y & 1, b = blockIdx.y >> 1;
  const int tc = l & 15, g = l >> 4;
  const int srcA = (((2 * g) & 3) << 4) | tc;
  const int srcB = (((2 * g + 1) & 3) << 4) | tc;

  // decode (qt16, ck)
  int qt16, ck;
  if (u < 32)       { qt16 = u;                   ck = 0; }
  else if (u < 96)  { int i = u - 32;  qt16 = 32 + (i >> 1); ck = i & 1; }
  else if (u < 192) { int i = u - 96;  int q3 = i / 3; qt16 = 64 + q3; ck = i - 3 * q3; }
  else              { int i = u - 192; qt16 = 96 + (i >> 2); ck = i & 3; }
  const int ntiles = (qt16 >> 2) + 1;
  const int nch    = (qt16 >> 5) + 1;
  const int tlo    = 8 * ck;
  const int thi    = (8 * ck + 8 < ntiles) ? (8 * ck + 8) : ntiles;
  const int ns     = thi - tlo;
  const bool dodiag = (ck == nch - 1);
  const bool split  = (nch > 1);

  const int h  = kv * 7 + w;
  const int qg = qt16 * 16 + tc;

  const uint16_t* Khead = Kb + (size_t)(b * NKV + kv) * S_ * HD;
  const uint16_t* Vhead = Vt + (size_t)(b * NKV + kv) * HD * S_;

  // 64x64 bf16 tile = 512 x 16B chunks: 448 lanes + wave0 covers 448..511.
  auto stage = [&](int t, int bi) {
    const int t0 = t * 64;
    #pragma unroll
    for (int i = 0; i < 2; ++i) {
      if (i == 0 || tid < 64) {                 // wave-uniform predicate
        int cid = i * 448 + tid;                // 0..511
        int row = cid >> 3, sch = (cid & 7) ^ (row & 7);
        GLOAD16(Khead + (size_t)(t0 + row) * HD + sch * 8, (char*)Ks[bi] + cid * 16);
        GLOAD16(Vhead + (size_t)row * S_ + t0 + sch * 8,   (char*)Vs[bi] + cid * 16);
      }
    }
  };

  // Q fragments (pre-scaled by QSCALE): lane owns one q-row (qg), d-slice g*8
  const uint16_t* qptr = Qb + ((size_t)(b * NH + h) * S_ + qg) * HD + g * 8;
  bf16x8 qf0 = *(const bf16x8*)qptr;
  bf16x8 qf1 = *(const bf16x8*)(qptr + 32);

  f32x4 oacc[4] = {};
  float mrow = -1e30f, lrow = 0.f;   // lane-partial over its 16 kv slots

  stage(tlo, 0);

  #pragma unroll 1
  for (int i = 0; i < ns; ++i) {
    const int t = tlo + i;
    asm volatile("s_waitcnt vmcnt(0)" ::: "memory");
    __builtin_amdgcn_s_barrier();
    if (i + 1 < ns) stage(t + 1, (i + 1) & 1);

    const uint16_t* Kc = Ks[i & 1];
    const uint16_t* Vc = Vs[i & 1];
    const int t0 = t * 64;

    // S^T = K * Q^T : sacc[c][r] = S[kv = t0 + c*16 + g*4 + r][q = qg]
    f32x4 sacc[4] = {};
    __builtin_amdgcn_s_setprio(1);
    #pragma unroll
    for (int ks = 0; ks < 2; ++ks) {
      bf16x8 qf = ks ? qf1 : qf0;
      #pragma unroll
      for (int c = 0; c < 4; ++c) {
        int trow = c * 16 + tc;
        int ch = (g + ks * 4) ^ (tc & 7);
        bf16x8 kf = *(const bf16x8*)((const char*)Kc + trow * 128 + ch * 16);
        sacc[c] = __builtin_amdgcn_mfma_f32_16x16x32_bf16(kf, qf, sacc[c], 0, 0, 0);
      }
    }
    __builtin_amdgcn_s_setprio(0);

    // causal mask on diagonal tile only
    if (dodiag && t == ntiles - 1) {
      #pragma unroll
      for (int c = 0; c < 4; ++c) {
        int kvb = t0 + c * 16 + g * 4;
        #pragma unroll
        for (int r = 0; r < 4; ++r)
          if (kvb + r > qg) sacc[c][r] = -1e30f;
      }
    }

    // T13 defer-max (exp2 domain, THR = 8*log2e ~ 11.5), native v_exp_f32
    float pmax = sacc[0][0];
    #pragma unroll
    for (int c = 0; c < 4; ++c)
      #pragma unroll
      for (int r = 0; r < 4; ++r) pmax = fmaxf(pmax, sacc[c][r]);
    if (__any(pmax > mrow + 11.5f)) {
      float mt = fmaxf(pmax, __shfl_xor(pmax, 16));
      mt = fmaxf(mt, __shfl_xor(mt, 32));
      float mn = fmaxf(mrow, mt);
      float corr = fexp2(mrow - mn);
      mrow = mn;
      lrow *= corr;
      #pragma unroll
      for (int dt = 0; dt < 4; ++dt) oacc[dt] *= corr;
    }
    float rs = 0.f;
    #pragma unroll
    for (int c = 0; c < 4; ++c)
      #pragma unroll
      for (int r = 0; r < 4; ++r) {
        float e = fexp2(sacc[c][r] - mrow);
        sacc[c][r] = e; rs += e;
      }
    lrow += rs;

    // pack P to bf16 words and redistribute into PV B-fragments
    uint32_t w0[4], w1[4];
    #pragma unroll
    for (int c = 0; c < 4; ++c) {
      w0[c] = pk2(sacc[c][0], sacc[c][1]);
      w1[c] = pk2(sacc[c][2], sacc[c][3]);
    }
    const bool lo = g < 2;
    bf16x8 pf[2];
    {
      union { uint32_t u[4]; bf16x8 v; } p0, p1;
      uint32_t a0 = __shfl((int)w0[0], srcA), a1 = __shfl((int)w1[0], srcA);
      uint32_t a2 = __shfl((int)w0[0], srcB), a3 = __shfl((int)w1[0], srcB);
      uint32_t b0 = __shfl((int)w0[1], srcA), b1 = __shfl((int)w1[1], srcA);
      uint32_t b2 = __shfl((int)w0[1], srcB), b3 = __shfl((int)w1[1], srcB);
      p0.u[0] = lo ? a0 : b0; p0.u[1] = lo ? a1 : b1;
      p0.u[2] = lo ? a2 : b2; p0.u[3] = lo ? a3 : b3;
      pf[0] = p0.v;
      uint32_t c0 = __shfl((int)w0[2], srcA), c1 = __shfl((int)w1[2], srcA);
      uint32_t c2 = __shfl((int)w0[2], srcB), c3 = __shfl((int)w1[2], srcB);
      uint32_t d0 = __shfl((int)w0[3], srcA), d1 = __shfl((int)w1[3], srcA);
      uint32_t d2 = __shfl((int)w0[3], srcB), d3 = __shfl((int)w1[3], srcB);
      p1.u[0] = lo ? c0 : d0; p1.u[1] = lo ? c1 : d1;
      p1.u[2] = lo ? c2 : d2; p1.u[3] = lo ? c3 : d3;
      pf[1] = p1.v;
    }

    // O^T += V^T * P^T
    __builtin_amdgcn_s_setprio(1);
    #pragma unroll
    for (int ks = 0; ks < 2; ++ks) {
      #pragma unroll
      for (int dt = 0; dt < 4; ++dt) {
        int drow = dt * 16 + tc;
        int vch = (g + ks * 4) ^ (tc & 7);
        bf16x8 vf = *(const bf16x8*)((const char*)Vc + drow * 128 + vch * 16);
        oacc[dt] = __builtin_amdgcn_mfma_f32_16x16x32_bf16(vf, pf[ks], oacc[dt], 0, 0, 0);
      }
    }
    __builtin_amdgcn_s_setprio(0);
  }

  // combine lane-partial lrow across the 4 lane-groups
  float ltot = lrow;
  ltot += __shfl_xor(ltot, 16);
  ltot += __shfl_xor(ltot, 32);

  if (!split) {
    float inv = 1.0f / ltot;
    size_t obase = (size_t)(b * S_ + qg) * HID + h * HD;
    #pragma unroll
    for (int dt = 0; dt < 4; ++dt) {
      union { uint16_t u[4]; uint64_t q; } o;
      #pragma unroll
      for (int r = 0; r < 4; ++r) o.u[r] = f2b(oacc[dt][r] * inv);
      *(uint64_t*)(Ob + obase + dt * 16 + g * 4) = o.q;
    }
  } else {
    // partial slot ck: unnormalized bf16 O + (m, l)  [m in log2 domain]
    size_t rowid = (size_t)(b * NH + h) * SROWS + (qg - 512);
    uint16_t* Opc = Op + (size_t)ck * OPSTR + rowid * 64;
    #pragma unroll
    for (int dt = 0; dt < 4; ++dt) {
      union { uint16_t u[4]; uint64_t q; } o;
      #pragma unroll
      for (int r = 0; r < 4; ++r) o.u[r] = f2b(oacc[dt][r]);
      *(uint64_t*)(Opc + dt * 16 + g * 4) = o.q;
    }
    if (g == 0) mlp[(size_t)ck * MLSTR + rowid] = make_float2(mrow, ltot);
  }
}

// ---------------- combine up to 4 partials for rows s >= 512 (exp2 domain) ----------------
__global__ void combine_kernel(const uint16_t* __restrict__ Op, const float2* __restrict__ mlp,
                               uint16_t* __restrict__ Ob) {
  int idx = blockIdx.x * 256 + threadIdx.x;   // B*NH*SROWS*16
  int r = idx >> 4;                           // (b*NH+h)*SROWS + (s-512)
  int d0 = (idx & 15) * 4;
  int bh = r / SROWS;
  int sr = r - bh * SROWS;
  int s = 512 + sr;
  int nch = (s >> 9) + 1;                     // 2..4
  float M = -1e30f;
  #pragma unroll 4
  for (int c = 0; c < 4; ++c)
    if (c < nch) M = fmaxf(M, mlp[(size_t)c * MLSTR + r].x);
  float den = 0.f, acc[4] = {0.f, 0.f, 0.f, 0.f};
  #pragma unroll 4
  for (int c = 0; c < 4; ++c) {
    if (c >= nch) continue;
    float2 ml = mlp[(size_t)c * MLSTR + r];
    float wg = fexp2(ml.x - M);
    den += ml.y * wg;
    union { uint16_t u[4]; uint64_t q; } o;
    o.q = *(const uint64_t*)(Op + (size_t)c * OPSTR + (size_t)r * 64 + d0);
    #pragma unroll
    for (int j = 0; j < 4; ++j) acc[j] += b2f(o.u[j]) * wg;
  }
  float inv = 1.0f / den;
  union { uint16_t u[4]; uint64_t q; } oo;
  #pragma unroll
  for (int j = 0; j < 4; ++j) oo.u[j] = f2b(acc[j] * inv);
  int bb = bh / NH, hh = bh - bb * NH;
  *(uint64_t*)(Ob + (size_t)(bb * S_ + s) * HID + hh * HD + d0) = oo.q;
}

// ---------------- launch ----------------
extern "C" void kernel_launch(void* const* d_in, const int* in_sizes, int n_in,
                              void* d_out, int out_size, void* d_ws, size_t ws_size,
                              hipStream_t stream) {
  (void)in_sizes; (void)n_in; (void)out_size; (void)ws_size;
  const float* X  = (const float*)d_in[0];
  // d_in[1] = attention_mask: pure causal tril, applied analytically in attn_kernel
  const float* Wq = (const float*)d_in[2];
  const float* bq = (const float*)d_in[3];
  const float* Wk = (const float*)d_in[4];
  const float* bk = (const float*)d_in[5];
  const float* Wv = (const float*)d_in[6];
  const float* bv = (const float*)d_in[7];
  const float* Wo = (const float*)d_in[8];
  const int* pos  = (const int*)d_in[9];

  char* p = (char*)d_ws;
  auto carve = [&](size_t n) -> char* { char* r = p; p += (n + 255) & ~(size_t)255; return r; };

  uint16_t* Xb    = (uint16_t*)carve((size_t)MROWS * HID * 2);
  uint16_t* WqkvT = (uint16_t*)carve((size_t)NQKV * 896 * 2);
  uint16_t* WoT   = (uint16_t*)carve((size_t)896 * 896 * 2);
  float*    bqkv  = (float*)carve((size_t)NQKV * 4);
  float*    cosT  = (float*)carve((size_t)S_ * 32 * 4);
  float*    sinT  = (float*)carve((size_t)S_ * 32 * 4);
  uint16_t* Qb    = (uint16_t*)carve((size_t)MROWS * HID * 2);
  uint16_t* Kb    = (uint16_t*)carve((size_t)MROWS * 128 * 2);
  uint16_t* Vf    = (uint16_t*)carve((size_t)MROWS * 128 * 2);
  uint16_t* Vt    = (uint16_t*)carve((size_t)MROWS * 128 * 2);
  uint16_t* Op    = (uint16_t*)carve((size_t)OPSTR * 4 * 2);
  float2*   mlp   = (float2*)carve((size_t)MLSTR * 4 * 8);
  uint16_t* Ob    = Xb;   // Xb dead after QKV gemm; attn/combine write Ob afterwards

  prep_all_kernel<<<dim3(5637), 256, 0, stream>>>(X, Wq, Wk, Wv, Wo, bq, bk, bv, pos,
                                                  Xb, WqkvT, WoT, bqkv, cosT, sinT);

  gemm_bt_kernel<1><<<dim3(MROWS / 128, NQKV / 64), 256, 0, stream>>>(
      Xb, WqkvT, bqkv, nullptr, NQKV, 896, cosT, sinT, Qb, Kb, Vf);

  packv_kernel<<<dim3(S_ / 64, BATCH * NKV), 256, 0, stream>>>(Vf, Vt);

  attn_kernel<<<dim3(320, NKV * BATCH), 448, 0, stream>>>(Qb, Kb, Vt, Ob, Op, mlp);
  combine_kernel<<<dim3(BATCH * NH * SROWS * 16 / 256), 256, 0, stream>>>(Op, mlp, Ob);

  gemm_bt_kernel<0><<<dim3(MROWS / 128, 896 / 64), 256, 0, stream>>>(
      Ob, WoT, nullptr, d_out, 896, 896, nullptr, nullptr, nullptr, nullptr, nullptr);
}

// Round 13
// 87.373 us; speedup vs baseline: 1.7577x; 1.0748x over previous
//
#include <hip/hip_runtime.h>
#include <stdint.h>

#define DEV __device__ __forceinline__

using bf16x8 = __attribute__((ext_vector_type(8))) short;
using f32x4  = __attribute__((ext_vector_type(4))) float;

DEV float b2f(uint16_t h){ return __uint_as_float(((uint32_t)h)<<16); }
DEV uint16_t f2b(float f){ uint32_t u=__float_as_uint(f); u += 0x7fffu + ((u>>16)&1u); return (uint16_t)(u>>16); }
// pack two f32 -> (bf16(a) | bf16(b)<<16), truncating round (1 v_perm_b32)
DEV uint32_t pk2(float a, float b){
  return __builtin_amdgcn_perm(__float_as_uint(b), __float_as_uint(a), 0x07060302u);
}
// native hardware exp2 (v_exp_f32 IS base-2): avoids libm exp2f's denormal-safe expansion
DEV float fexp2(float x){ float r; asm("v_exp_f32 %0, %1" : "=v"(r) : "v"(x)); return r; }

// async global->LDS, 16B per lane; LDS dest must be wave-uniform base + lane*16
#define GLOAD16(gp, lp) __builtin_amdgcn_global_load_lds( \
    (__attribute__((address_space(1))) void*)(gp), \
    (__attribute__((address_space(3))) void*)(lp), 16, 0, 0)

constexpr int S_    = 2048;
constexpr int HID   = 896;
constexpr int NH    = 14;
constexpr int NKV   = 2;
constexpr int HD    = 64;
constexpr int BATCH = 2;
constexpr int MROWS = BATCH * S_;   // 4096
constexpr int NQKV  = 1152;         // 896 + 128 + 128
constexpr int SROWS = 1536;         // rows s in [512,2048) have split partials
constexpr int OPSTR = BATCH * NH * SROWS * 64;   // elements per partial slot
constexpr int MLSTR = BATCH * NH * SROWS;        // float2 per partial slot
// log2(e) folded into Q scale: scores in log2-domain, exp -> native exp2
constexpr float QSCALE = 0.125f * 1.4426950408889634f;

// ---- merged prep: weight pack (0..1791) | cvt_x (1792..5375) | rope (5376..5631) | bias (5632..5636)
__global__ void prep_all_kernel(const float* __restrict__ X,
                                const float* __restrict__ Wq, const float* __restrict__ Wk,
                                const float* __restrict__ Wv, const float* __restrict__ Wo,
                                const float* __restrict__ bq, const float* __restrict__ bk,
                                const float* __restrict__ bv, const int* __restrict__ pos0,
                                uint16_t* __restrict__ Xb,
                                uint16_t* __restrict__ WqkvT, uint16_t* __restrict__ WoT,
                                float* __restrict__ bqkv,
                                float* __restrict__ cosT, float* __restrict__ sinT) {
  const int blk = blockIdx.x, tid = threadIdx.x;
  if (blk < 1792) {                                // weight pack (32x32 tile transpose)
    const int lx = tid & 31, ly = tid >> 5;        // 32 x 8
    const float* src; uint16_t* dst; int ncols, rowOff, i;
    if (blk < 784)       { src = Wq; dst = WqkvT; ncols = 896; rowOff = 0;    i = blk;       }
    else if (blk < 896)  { src = Wk; dst = WqkvT; ncols = 128; rowOff = 896;  i = blk - 784; }
    else if (blk < 1008) { src = Wv; dst = WqkvT; ncols = 128; rowOff = 1024; i = blk - 896; }
    else                 { src = Wo; dst = WoT;   ncols = 896; rowOff = 0;    i = blk - 1008;}
    const int nb = ncols >> 5;
    const int n0 = (i % nb) * 32, k0 = (i / nb) * 32;
    __shared__ uint16_t tile[32][33];
    #pragma unroll
    for (int r = 0; r < 32; r += 8)
      tile[ly + r][lx] = f2b(src[(size_t)(k0 + ly + r) * ncols + (n0 + lx)]);
    __syncthreads();
    #pragma unroll
    for (int r = 0; r < 32; r += 8)
      dst[(size_t)(rowOff + n0 + ly + r) * 896 + (k0 + lx)] = tile[lx][ly + r];
  } else if (blk < 5376) {                         // cvt_x: f32 -> bf16, 4/thread
    int i = (blk - 1792) * 256 + tid;
    float4 v = ((const float4*)X)[i];
    union { uint16_t u[4]; uint64_t q; } r;
    r.u[0] = f2b(v.x); r.u[1] = f2b(v.y); r.u[2] = f2b(v.z); r.u[3] = f2b(v.w);
    ((uint64_t*)Xb)[i] = r.q;
  } else if (blk < 5632) {                         // rope table
    int idx = (blk - 5376) * 256 + tid;            // S*32
    int s = idx >> 5, j = idx & 31;
    float inv = exp2f(-(float)j * (19.931568569324174f / 32.0f));  // 1e6^(-j/32)
    float ang = (float)(pos0[0] + s) * inv;
    float sv, cv;
    sincosf(ang, &sv, &cv);
    cosT[idx] = cv; sinT[idx] = sv;
  } else {                                         // bias concat
    int i = (blk - 5632) * 256 + tid;
    if (i < NQKV) bqkv[i] = i < 896 ? bq[i] : (i < 1024 ? bk[i - 896] : bv[i - 1024]);
  }
}

// ---------------- V: Vf (B,S,128) -> V^T (B,KV,D,S), bit-permuted columns ----------------
// Column permutation inside each 64-tile matches the PV B-fragment's own-lane kv order:
// col(s) = s5*32 + s3*16 + s2*8 + s4*4 + (s&3)  (bijective), so the attn kernel needs
// ZERO shuffles to build the P fragment (each lane's own 16 P-values fill its B slots).
__global__ void packv_kernel(const uint16_t* __restrict__ Vf, uint16_t* __restrict__ Vt) {
  __shared__ uint16_t tile[64][65];
  const int s0 = blockIdx.x * 64;
  const int g  = blockIdx.y;                  // b*NKV + kv
  const int b = g >> 1, kv = g & 1;
  const int lx = threadIdx.x & 63, ly = threadIdx.x >> 6;   // 64 x 4
  #pragma unroll
  for (int i = 0; i < 64; i += 4)
    tile[ly + i][lx] = Vf[(size_t)(b * S_ + s0 + ly + i) * 128 + kv * 64 + lx];
  __syncthreads();
  const int col = (lx & 32) | ((lx & 8) << 1) | ((lx & 4) << 1) | ((lx & 16) >> 2) | (lx & 3);
  #pragma unroll
  for (int i = 0; i < 64; i += 4)
    Vt[((size_t)g * HD + ly + i) * S_ + s0 + col] = tile[lx][ly + i];
}

// ---------------- GEMM: C(MxN) = A(MxK,bf16) * Bt(NxK,bf16)^T + bias ----------------
// Tile 128x64, 4 waves of 32x64 (acc[2][4]); double-buffered LDS 2-phase pipeline.
template <int EPI>
__global__ __launch_bounds__(256) void gemm_bt_kernel(
    const uint16_t* __restrict__ A, const uint16_t* __restrict__ Bt,
    const float* __restrict__ bias, void* __restrict__ Cv, int N, int K,
    const float* __restrict__ cosT, const float* __restrict__ sinT,
    uint16_t* __restrict__ Qb, uint16_t* __restrict__ Kb, uint16_t* __restrict__ Vf) {
  __shared__ __align__(16) uint16_t As[2][128 * 64];   // 32 KB
  __shared__ __align__(16) uint16_t Bs[2][64 * 64];    // 16 KB
  const int tid = threadIdx.x;
  const int l = tid & 63, w = tid >> 6;
  const int m0 = blockIdx.x * 128, n0 = blockIdx.y * 64;
  const int wr = w * 32;                            // 32 rows per wave, all 64 cols

  auto stage = [&](int k0, int bi) {
    #pragma unroll
    for (int i = 0; i < 4; ++i) {
      int cid = i * 256 + tid;                 // 1024 A-chunks
      int row = cid >> 3;
      int sch = (cid & 7) ^ (row & 7);
      GLOAD16(A + (size_t)(m0 + row) * K + (k0 + sch * 8), (char*)As[bi] + cid * 16);
    }
    #pragma unroll
    for (int i = 0; i < 2; ++i) {
      int cid = i * 256 + tid;                 // 512 B-chunks
      int row = cid >> 3;
      int sch = (cid & 7) ^ (row & 7);
      GLOAD16(Bt + (size_t)(n0 + row) * K + (k0 + sch * 8), (char*)Bs[bi] + cid * 16);
    }
  };

  const int nk = K >> 6;
  f32x4 acc[2][4] = {};
  stage(0, 0);
  asm volatile("s_waitcnt vmcnt(0)" ::: "memory");
  __builtin_amdgcn_s_barrier();

  #pragma unroll 1
  for (int t = 0; t < nk; ++t) {
    if (t + 1 < nk) stage((t + 1) << 6, (t + 1) & 1);   // overlap with compute
    const uint16_t* Ac = As[t & 1];
    const uint16_t* Bc = Bs[t & 1];
    __builtin_amdgcn_s_setprio(1);
    #pragma unroll
    for (int ks = 0; ks < 2; ++ks) {
      bf16x8 af[2], bfr[4];
      #pragma unroll
      for (int mi = 0; mi < 2; ++mi) {
        int row = wr + mi * 16 + (l & 15);
        int ch = ((l >> 4) + ks * 4) ^ (row & 7);
        af[mi] = *(const bf16x8*)((const char*)Ac + row * 128 + ch * 16);
      }
      #pragma unroll
      for (int ni = 0; ni < 4; ++ni) {
        int row = ni * 16 + (l & 15);
        int ch = ((l >> 4) + ks * 4) ^ (row & 7);
        bfr[ni] = *(const bf16x8*)((const char*)Bc + row * 128 + ch * 16);
      }
      #pragma unroll
      for (int mi = 0; mi < 2; ++mi)
        #pragma unroll
        for (int ni = 0; ni < 4; ++ni)
          acc[mi][ni] = __builtin_amdgcn_mfma_f32_16x16x32_bf16(af[mi], bfr[ni], acc[mi][ni], 0, 0, 0);
    }
    __builtin_amdgcn_s_setprio(0);
    asm volatile("s_waitcnt vmcnt(0)" ::: "memory");   // next tile landed
    __builtin_amdgcn_s_barrier();                      // all waves done with buf[t&1]
  }

  const int tc = l & 15, g = l >> 4;
  if (EPI == 1) {
    if (n0 < 896) {
      // Q head h = n0>>6: RoPE pairs (ni, ni+2), scale QSCALE (1/8 * log2e)
      #pragma unroll
      for (int mi = 0; mi < 2; ++mi) {
        #pragma unroll
        for (int jr = 0; jr < 4; ++jr) {
          int row = m0 + wr + mi * 16 + g * 4 + jr;
          int bb = row >> 11, s = row & (S_ - 1);
          const float* cp = cosT + s * 32;
          const float* sp = sinT + s * 32;
          #pragma unroll
          for (int ni = 0; ni < 2; ++ni) {
            int col = n0 + ni * 16 + tc;
            int j = col & 63;   // < 32
            float c = cp[j], sn = sp[j];
            float alo = acc[mi][ni][jr] + bias[col];
            float ahi = acc[mi][ni + 2][jr] + bias[col + 32];
            size_t dst = ((size_t)(bb * NH + (n0 >> 6)) * S_ + s) * HD + j;
            Qb[dst]      = f2b((alo * c - ahi * sn) * QSCALE);
            Qb[dst + 32] = f2b((ahi * c + alo * sn) * QSCALE);
          }
        }
      }
    } else if (n0 < 1024) {
      // K head kvh = (n0-896)>>6: RoPE, no scale
      #pragma unroll
      for (int mi = 0; mi < 2; ++mi) {
        #pragma unroll
        for (int jr = 0; jr < 4; ++jr) {
          int row = m0 + wr + mi * 16 + g * 4 + jr;
          int bb = row >> 11, s = row & (S_ - 1);
          const float* cp = cosT + s * 32;
          const float* sp = sinT + s * 32;
          #pragma unroll
          for (int ni = 0; ni < 2; ++ni) {
            int col = n0 + ni * 16 + tc;
            int j = col & 63;   // < 32
            float c = cp[j], sn = sp[j];
            float alo = acc[mi][ni][jr] + bias[col];
            float ahi = acc[mi][ni + 2][jr] + bias[col + 32];
            size_t dst = ((size_t)(bb * NKV + ((n0 - 896) >> 6)) * S_ + s) * HD + j;
            Kb[dst]      = f2b(alo * c - ahi * sn);
            Kb[dst + 32] = f2b(ahi * c + alo * sn);
          }
        }
      }
    } else {
      // V block: plain bf16, row-major Vf (B*S, 128)
      #pragma unroll
      for (int mi = 0; mi < 2; ++mi)
        #pragma unroll
        for (int ni = 0; ni < 4; ++ni) {
          int col = n0 + ni * 16 + tc;
          #pragma unroll
          for (int jr = 0; jr < 4; ++jr) {
            int row = m0 + wr + mi * 16 + g * 4 + jr;
            Vf[(size_t)row * 128 + (col - 1024)] = f2b(acc[mi][ni][jr] + bias[col]);
          }
        }
    }
  } else {
    #pragma unroll
    for (int mi = 0; mi < 2; ++mi) {
      #pragma unroll
      for (int ni = 0; ni < 4; ++ni) {
        int col = n0 + ni * 16 + tc;
        #pragma unroll
        for (int j = 0; j < 4; ++j) {
          int row = m0 + wr + mi * 16 + g * 4 + j;
          ((float*)Cv)[(size_t)row * N + col] = acc[mi][ni][j];
        }
      }
    }
  }
}

// ---------------- Flash attention v13: zero-shuffle P->PV ----------------
// Block = 448 threads, wave w = head kv*7+w, shared K/V LDS tile, depth-1 prefetch.
// Swapped QK^T puts P[kv = c*16+g*4+r][q=tc] in lane (g,tc); V columns are stored
// bit-permuted (packv) so slot(ks,g,j) <-> kv = 32ks+16(j>>2)+4g+(j&3): the B-fragment
// assembles from the lane's OWN registers. Removes 16 ds_bpermute + 8 selects/step.
__global__ __launch_bounds__(448) void attn_kernel(
    const uint16_t* __restrict__ Qb, const uint16_t* __restrict__ Kb,
    const uint16_t* __restrict__ Vt, uint16_t* __restrict__ Ob,
    uint16_t* __restrict__ Op, float2* __restrict__ mlp) {
  __shared__ __align__(16) uint16_t Ks[2][64 * 64];   // [kv][d], swizzled
  __shared__ __align__(16) uint16_t Vs[2][64 * 64];   // [d][kv-permuted], swizzled
  const int tid = threadIdx.x, l = tid & 63, w = tid >> 6;
  const int u = blockIdx.x;
  const int kv = blockIdx.y & 1, b = blockIdx.y >> 1;
  const int tc = l & 15, g = l >> 4;

  // decode (qt16, ck)
  int qt16, ck;
  if (u < 32)       { qt16 = u;                   ck = 0; }
  else if (u < 96)  { int i = u - 32;  qt16 = 32 + (i >> 1); ck = i & 1; }
  else if (u < 192) { int i = u - 96;  int q3 = i / 3; qt16 = 64 + q3; ck = i - 3 * q3; }
  else              { int i = u - 192; qt16 = 96 + (i >> 2); ck = i & 3; }
  const int ntiles = (qt16 >> 2) + 1;
  const int nch    = (qt16 >> 5) + 1;
  const int tlo    = 8 * ck;
  const int thi    = (8 * ck + 8 < ntiles) ? (8 * ck + 8) : ntiles;
  const int ns     = thi - tlo;
  const bool dodiag = (ck == nch - 1);
  const bool split  = (nch > 1);

  const int h  = kv * 7 + w;
  const int qg = qt16 * 16 + tc;

  const uint16_t* Khead = Kb + (size_t)(b * NKV + kv) * S_ * HD;
  const uint16_t* Vhead = Vt + (size_t)(b * NKV + kv) * HD * S_;

  // 64x64 bf16 tile = 512 x 16B chunks: 448 lanes + wave0 covers 448..511.
  auto stage = [&](int t, int bi) {
    const int t0 = t * 64;
    #pragma unroll
    for (int i = 0; i < 2; ++i) {
      if (i == 0 || tid < 64) {                 // wave-uniform predicate
        int cid = i * 448 + tid;                // 0..511
        int row = cid >> 3, sch = (cid & 7) ^ (row & 7);
        GLOAD16(Khead + (size_t)(t0 + row) * HD + sch * 8, (char*)Ks[bi] + cid * 16);
        GLOAD16(Vhead + (size_t)row * S_ + t0 + sch * 8,   (char*)Vs[bi] + cid * 16);
      }
    }
  };

  // Q fragments (pre-scaled by QSCALE): lane owns one q-row (qg), d-slice g*8
  const uint16_t* qptr = Qb + ((size_t)(b * NH + h) * S_ + qg) * HD + g * 8;
  bf16x8 qf0 = *(const bf16x8*)qptr;
  bf16x8 qf1 = *(const bf16x8*)(qptr + 32);

  f32x4 oacc[4] = {};
  float mrow = -1e30f, lrow = 0.f;   // lane-partial over its 16 kv slots

  stage(tlo, 0);

  #pragma unroll 1
  for (int i = 0; i < ns; ++i) {
    const int t = tlo + i;
    asm volatile("s_waitcnt vmcnt(0)" ::: "memory");
    __builtin_amdgcn_s_barrier();
    if (i + 1 < ns) stage(t + 1, (i + 1) & 1);

    const uint16_t* Kc = Ks[i & 1];
    const uint16_t* Vc = Vs[i & 1];
    const int t0 = t * 64;

    // S^T = K * Q^T : sacc[c][r] = S[kv = t0 + c*16 + g*4 + r][q = qg]
    f32x4 sacc[4] = {};
    __builtin_amdgcn_s_setprio(1);
    #pragma unroll
    for (int ks = 0; ks < 2; ++ks) {
      bf16x8 qf = ks ? qf1 : qf0;
      #pragma unroll
      for (int c = 0; c < 4; ++c) {
        int trow = c * 16 + tc;
        int ch = (g + ks * 4) ^ (tc & 7);
        bf16x8 kf = *(const bf16x8*)((const char*)Kc + trow * 128 + ch * 16);
        sacc[c] = __builtin_amdgcn_mfma_f32_16x16x32_bf16(kf, qf, sacc[c], 0, 0, 0);
      }
    }
    __builtin_amdgcn_s_setprio(0);

    // causal mask on diagonal tile only
    if (dodiag && t == ntiles - 1) {
      #pragma unroll
      for (int c = 0; c < 4; ++c) {
        int kvb = t0 + c * 16 + g * 4;
        #pragma unroll
        for (int r = 0; r < 4; ++r)
          if (kvb + r > qg) sacc[c][r] = -1e30f;
      }
    }

    // T13 defer-max (exp2 domain, THR = 8*log2e ~ 11.5), native v_exp_f32
    float pmax = sacc[0][0];
    #pragma unroll
    for (int c = 0; c < 4; ++c)
      #pragma unroll
      for (int r = 0; r < 4; ++r) pmax = fmaxf(pmax, sacc[c][r]);
    if (__any(pmax > mrow + 11.5f)) {
      float mt = fmaxf(pmax, __shfl_xor(pmax, 16));
      mt = fmaxf(mt, __shfl_xor(mt, 32));
      float mn = fmaxf(mrow, mt);
      float corr = fexp2(mrow - mn);
      mrow = mn;
      lrow *= corr;
      #pragma unroll
      for (int dt = 0; dt < 4; ++dt) oacc[dt] *= corr;
    }
    float rs = 0.f;
    #pragma unroll
    for (int c = 0; c < 4; ++c)
      #pragma unroll
      for (int r = 0; r < 4; ++r) {
        float e = fexp2(sacc[c][r] - mrow);
        sacc[c][r] = e; rs += e;
      }
    lrow += rs;

    // P -> bf16 B-fragments from OWN registers (V column order matches by construction)
    uint32_t w0[4], w1[4];
    #pragma unroll
    for (int c = 0; c < 4; ++c) {
      w0[c] = pk2(sacc[c][0], sacc[c][1]);
      w1[c] = pk2(sacc[c][2], sacc[c][3]);
    }
    bf16x8 pf[2];
    {
      union { uint32_t u[4]; bf16x8 v; } p0, p1;
      p0.u[0] = w0[0]; p0.u[1] = w1[0]; p0.u[2] = w0[1]; p0.u[3] = w1[1];
      p1.u[0] = w0[2]; p1.u[1] = w1[2]; p1.u[2] = w0[3]; p1.u[3] = w1[3];
      pf[0] = p0.v; pf[1] = p1.v;
    }

    // O^T += V^T * P^T
    __builtin_amdgcn_s_setprio(1);
    #pragma unroll
    for (int ks = 0; ks < 2; ++ks) {
      #pragma unroll
      for (int dt = 0; dt < 4; ++dt) {
        int drow = dt * 16 + tc;
        int vch = (g + ks * 4) ^ (tc & 7);
        bf16x8 vf = *(const bf16x8*)((const char*)Vc + drow * 128 + vch * 16);
        oacc[dt] = __builtin_amdgcn_mfma_f32_16x16x32_bf16(vf, pf[ks], oacc[dt], 0, 0, 0);
      }
    }
    __builtin_amdgcn_s_setprio(0);
  }

  // combine lane-partial lrow across the 4 lane-groups
  float ltot = lrow;
  ltot += __shfl_xor(ltot, 16);
  ltot += __shfl_xor(ltot, 32);

  if (!split) {
    float inv = 1.0f / ltot;
    size_t obase = (size_t)(b * S_ + qg) * HID + h * HD;
    #pragma unroll
    for (int dt = 0; dt < 4; ++dt) {
      union { uint16_t u[4]; uint64_t q; } o;
      #pragma unroll
      for (int r = 0; r < 4; ++r) o.u[r] = f2b(oacc[dt][r] * inv);
      *(uint64_t*)(Ob + obase + dt * 16 + g * 4) = o.q;
    }
  } else {
    // partial slot ck: unnormalized bf16 O + (m, l)  [m in log2 domain]
    size_t rowid = (size_t)(b * NH + h) * SROWS + (qg - 512);
    uint16_t* Opc = Op + (size_t)ck * OPSTR + rowid * 64;
    #pragma unroll
    for (int dt = 0; dt < 4; ++dt) {
      union { uint16_t u[4]; uint64_t q; } o;
      #pragma unroll
      for (int r = 0; r < 4; ++r) o.u[r] = f2b(oacc[dt][r]);
      *(uint64_t*)(Opc + dt * 16 + g * 4) = o.q;
    }
    if (g == 0) mlp[(size_t)ck * MLSTR + rowid] = make_float2(mrow, ltot);
  }
}

// ---------------- combine up to 4 partials for rows s >= 512 (exp2 domain) ----------------
__global__ void combine_kernel(const uint16_t* __restrict__ Op, const float2* __restrict__ mlp,
                               uint16_t* __restrict__ Ob) {
  int idx = blockIdx.x * 256 + threadIdx.x;   // B*NH*SROWS*16
  int r = idx >> 4;                           // (b*NH+h)*SROWS + (s-512)
  int d0 = (idx & 15) * 4;
  int bh = r / SROWS;
  int sr = r - bh * SROWS;
  int s = 512 + sr;
  int nch = (s >> 9) + 1;                     // 2..4
  float M = -1e30f;
  #pragma unroll 4
  for (int c = 0; c < 4; ++c)
    if (c < nch) M = fmaxf(M, mlp[(size_t)c * MLSTR + r].x);
  float den = 0.f, acc[4] = {0.f, 0.f, 0.f, 0.f};
  #pragma unroll 4
  for (int c = 0; c < 4; ++c) {
    if (c >= nch) continue;
    float2 ml = mlp[(size_t)c * MLSTR + r];
    float wg = fexp2(ml.x - M);
    den += ml.y * wg;
    union { uint16_t u[4]; uint64_t q; } o;
    o.q = *(const uint64_t*)(Op + (size_t)c * OPSTR + (size_t)r * 64 + d0);
    #pragma unroll
    for (int j = 0; j < 4; ++j) acc[j] += b2f(o.u[j]) * wg;
  }
  float inv = 1.0f / den;
  union { uint16_t u[4]; uint64_t q; } oo;
  #pragma unroll
  for (int j = 0; j < 4; ++j) oo.u[j] = f2b(acc[j] * inv);
  int bb = bh / NH, hh = bh - bb * NH;
  *(uint64_t*)(Ob + (size_t)(bb * S_ + s) * HID + hh * HD + d0) = oo.q;
}

// ---------------- launch ----------------
extern "C" void kernel_launch(void* const* d_in, const int* in_sizes, int n_in,
                              void* d_out, int out_size, void* d_ws, size_t ws_size,
                              hipStream_t stream) {
  (void)in_sizes; (void)n_in; (void)out_size; (void)ws_size;
  const float* X  = (const float*)d_in[0];
  // d_in[1] = attention_mask: pure causal tril, applied analytically in attn_kernel
  const float* Wq = (const float*)d_in[2];
  const float* bq = (const float*)d_in[3];
  const float* Wk = (const float*)d_in[4];
  const float* bk = (const float*)d_in[5];
  const float* Wv = (const float*)d_in[6];
  const float* bv = (const float*)d_in[7];
  const float* Wo = (const float*)d_in[8];
  const int* pos  = (const int*)d_in[9];

  char* p = (char*)d_ws;
  auto carve = [&](size_t n) -> char* { char* r = p; p += (n + 255) & ~(size_t)255; return r; };

  uint16_t* Xb    = (uint16_t*)carve((size_t)MROWS * HID * 2);
  uint16_t* WqkvT = (uint16_t*)carve((size_t)NQKV * 896 * 2);
  uint16_t* WoT   = (uint16_t*)carve((size_t)896 * 896 * 2);
  float*    bqkv  = (float*)carve((size_t)NQKV * 4);
  float*    cosT  = (float*)carve((size_t)S_ * 32 * 4);
  float*    sinT  = (float*)carve((size_t)S_ * 32 * 4);
  uint16_t* Qb    = (uint16_t*)carve((size_t)MROWS * HID * 2);
  uint16_t* Kb    = (uint16_t*)carve((size_t)MROWS * 128 * 2);
  uint16_t* Vf    = (uint16_t*)carve((size_t)MROWS * 128 * 2);
  uint16_t* Vt    = (uint16_t*)carve((size_t)MROWS * 128 * 2);
  uint16_t* Op    = (uint16_t*)carve((size_t)OPSTR * 4 * 2);
  float2*   mlp   = (float2*)carve((size_t)MLSTR * 4 * 8);
  uint16_t* Ob    = Xb;   // Xb dead after QKV gemm; attn/combine write Ob afterwards

  prep_all_kernel<<<dim3(5637), 256, 0, stream>>>(X, Wq, Wk, Wv, Wo, bq, bk, bv, pos,
                                                  Xb, WqkvT, WoT, bqkv, cosT, sinT);

  gemm_bt_kernel<1><<<dim3(MROWS / 128, NQKV / 64), 256, 0, stream>>>(
      Xb, WqkvT, bqkv, nullptr, NQKV, 896, cosT, sinT, Qb, Kb, Vf);

  packv_kernel<<<dim3(S_ / 64, BATCH * NKV), 256, 0, stream>>>(Vf, Vt);

  attn_kernel<<<dim3(320, NKV * BATCH), 448, 0, stream>>>(Qb, Kb, Vt, Ob, Op, mlp);
  combine_kernel<<<dim3(BATCH * NH * SROWS * 16 / 256), 256, 0, stream>>>(Op, mlp, Ob);

  gemm_bt_kernel<0><<<dim3(MROWS / 128, 896 / 64), 256, 0, stream>>>(
      Ob, WoT, nullptr, d_out, 896, 896, nullptr, nullptr, nullptr, nullptr, nullptr);
}